// Round 3
// baseline (5379.247 us; speedup 1.0000x reference)
//
#include <hip/hip_runtime.h>
#include <math.h>

static constexpr int L_SEQ  = 3136;
static constexpr int NBATCH = 8;
static constexpr int CDIM   = 384;
static constexpr int DIN    = 768;
static constexpr int NHM    = 12;
static constexpr int HDM    = 64;
static constexpr int DPROJ  = 1676;   // 2*768 + 2*64 + 12
static constexpr int CONVD  = 896;    // 768 + 128
static constexpr int NROWS  = NBATCH * L_SEQ; // 25088
static constexpr int NHA    = 12;     // attention heads
static constexpr int CHROWS = 6272;   // 2 batches per chunk (49 * 128)
static constexpr int NCHUNK = 4;

__device__ __forceinline__ float siluf(float x) { return x / (1.f + __expf(-x)); }

// ---------------- LayerNorm: one wave per row, C=384 ----------------
__global__ __launch_bounds__(256) void ln_kernel(const float* __restrict__ in,
    const float* __restrict__ w, const float* __restrict__ b, float* __restrict__ out) {
  int wave = threadIdx.x >> 6, lane = threadIdx.x & 63;
  int row = blockIdx.x * 4 + wave;
  if (row >= NROWS) return;
  const float* r = in + (size_t)row * CDIM;
  float2 v[3];
  float s1 = 0.f, s2 = 0.f;
#pragma unroll
  for (int q = 0; q < 3; q++) {
    v[q] = *(const float2*)&r[q * 128 + lane * 2];
    s1 += v[q].x + v[q].y;
    s2 += v[q].x * v[q].x + v[q].y * v[q].y;
  }
#pragma unroll
  for (int o = 32; o > 0; o >>= 1) { s1 += __shfl_xor(s1, o, 64); s2 += __shfl_xor(s2, o, 64); }
  float mu = s1 * (1.f / 384.f);
  float var = s2 * (1.f / 384.f) - mu * mu;
  float rs = rsqrtf(var + 1e-5f);
  float* o = out + (size_t)row * CDIM;
#pragma unroll
  for (int q = 0; q < 3; q++) {
    int c = q * 128 + lane * 2;
    float2 wv = *(const float2*)&w[c];
    float2 bv = *(const float2*)&b[c];
    float2 ov;
    ov.x = (v[q].x - mu) * rs * wv.x + bv.x;
    ov.y = (v[q].y - mu) * rs * wv.y + bv.y;
    *(float2*)&o[c] = ov;
  }
}

// ---------------- Generic fp32 GEMM: C[m, coff+n] = act(A@W + bias) + res ----------------
// 128x128 tile, BK=8, 256 threads, 8x8 microtile.
// Requires: M % 128 == 0, K % 8 == 0, lda % 4 == 0, ldw % 4 == 0. N may be ragged.
template<int ACT, bool HASBIAS, bool HASRES>
__global__ __launch_bounds__(256) void gemm_k(
    const float* __restrict__ A, const float* __restrict__ W,
    float* __restrict__ C, const float* __restrict__ bias,
    const float* __restrict__ res, int ldr,
    int M, int N, int K, int lda, int ldw, int ldc, int coff)
{
  __shared__ float As[8][128];
  __shared__ float Ws[8][128];
  int t = threadIdx.x;
  int m0 = blockIdx.y * 128, n0 = blockIdx.x * 128;
  float acc[8][8] = {};
  int tm = t >> 4, tn = t & 15;
  int am = t >> 1, akq = (t & 1) * 4;
  int wk = t >> 5, wn = (t & 31) * 4;
  for (int k0 = 0; k0 < K; k0 += 8) {
    float4 a4 = *(const float4*)&A[(size_t)(m0 + am) * lda + k0 + akq];
    As[akq + 0][am] = a4.x; As[akq + 1][am] = a4.y;
    As[akq + 2][am] = a4.z; As[akq + 3][am] = a4.w;
    int wcol = n0 + wn;
    if (wcol + 3 < N) {
      *(float4*)&Ws[wk][wn] = *(const float4*)&W[(size_t)(k0 + wk) * ldw + wcol];
    } else {
#pragma unroll
      for (int j = 0; j < 4; j++)
        Ws[wk][wn + j] = (wcol + j < N) ? W[(size_t)(k0 + wk) * ldw + wcol + j] : 0.f;
    }
    __syncthreads();
#pragma unroll
    for (int k = 0; k < 8; k++) {
      float4 a0 = *(const float4*)&As[k][tm * 8];
      float4 a1 = *(const float4*)&As[k][tm * 8 + 4];
      float4 w0 = *(const float4*)&Ws[k][tn * 4];
      float4 w1 = *(const float4*)&Ws[k][64 + tn * 4];
      float av[8] = {a0.x, a0.y, a0.z, a0.w, a1.x, a1.y, a1.z, a1.w};
      float wv[8] = {w0.x, w0.y, w0.z, w0.w, w1.x, w1.y, w1.z, w1.w};
#pragma unroll
      for (int i = 0; i < 8; i++)
#pragma unroll
        for (int j = 0; j < 8; j++)
          acc[i][j] += av[i] * wv[j];
    }
    __syncthreads();
  }
#pragma unroll
  for (int i = 0; i < 8; i++) {
    int m = m0 + tm * 8 + i;
#pragma unroll
    for (int jh = 0; jh < 2; jh++) {
#pragma unroll
      for (int jl = 0; jl < 4; jl++) {
        int n = n0 + jh * 64 + tn * 4 + jl;
        if (n >= N) continue;
        float v = acc[i][jh * 4 + jl];
        if (HASBIAS) v += bias[n];
        if (ACT == 1) v = 0.5f * v * (1.f + erff(v * 0.70710678118654752f));
        if (HASRES) v += res[(size_t)m * ldr + n];
        C[(size_t)m * ldc + coff + n] = v;
      }
    }
  }
}

// ---------------- dt prep (in-place): DT=softplus(DT+bias), DA=exp(-exp(A_log)*DT) ----------------
__global__ void dtprep_kernel(float* __restrict__ DT, const float* __restrict__ dt_bias,
    const float* __restrict__ A_log, float* __restrict__ DA) {
  int idx = blockIdx.x * blockDim.x + threadIdx.x;
  if (idx >= NROWS * NHM) return;
  int h = idx % NHM;
  float v = DT[idx] + dt_bias[h];
  float sp = (v > 20.f) ? v : log1pf(expf(v));
  DT[idx] = sp;
  DA[idx] = expf(-expf(A_log[h]) * sp);
}

// ---------------- depthwise causal conv (k=4) + bias + silu; one 2-batch chunk ----------------
__global__ void conv_kernel(const float* __restrict__ xbc, const float* __restrict__ cw,
    const float* __restrict__ cb, float* __restrict__ XC) {
  int idx = blockIdx.x * blockDim.x + threadIdx.x;
  if (idx >= CHROWS * CONVD) return;
  int c = idx % CONVD;
  int row = idx / CONVD;          // chunk-local row
  int l = row % L_SEQ;            // position within batch (chunk = whole batches)
  float acc = cb[c];
#pragma unroll
  for (int j = 0; j < 4; j++) {
    int ls = l - 3 + j;
    if (ls >= 0) acc += xbc[(size_t)(row - 3 + j) * CONVD + c] * cw[c * 4 + j];
  }
  XC[(size_t)row * CONVD + c] = siluf(acc);
}

// ---------------- SSM sequential scan (full batch) ----------------
__global__ __launch_bounds__(256) void scan_kernel(const float* __restrict__ XC,
    const float* __restrict__ dtp, const float* __restrict__ dAv,
    const float* __restrict__ Dp, float* __restrict__ Y) {
  int bid = blockIdx.x;
  int b = bid / (NHM * 4);
  int r = bid - b * (NHM * 4);
  int head = r >> 2, ps = r & 3;
  int t = threadIdx.x;
  int pl = t >> 4, ng = t & 15;
  int p = ps * 16 + pl, n0 = ng * 4;
  float Dh = Dp[head];
  float h0 = 0.f, h1 = 0.f, h2 = 0.f, h3 = 0.f;
  const float* xcb = XC + (size_t)b * L_SEQ * CONVD;
  const float* dtb = dtp + (size_t)b * L_SEQ * NHM + head;
  const float* dab = dAv + (size_t)b * L_SEQ * NHM + head;
  float* yb = Y + (size_t)b * L_SEQ * DIN + head * HDM + p;
  int xcol = head * HDM + p;
  for (int l = 0; l < L_SEQ; l++) {
    const float* rowp = xcb + (size_t)l * CONVD;
    float xv = rowp[xcol];
    float4 Bv = *(const float4*)&rowp[768 + n0];
    float4 Cv = *(const float4*)&rowp[832 + n0];
    float dtv = dtb[(size_t)l * NHM];
    float dav = dab[(size_t)l * NHM];
    float a = dtv * xv;
    h0 = h0 * dav + a * Bv.x;
    h1 = h1 * dav + a * Bv.y;
    h2 = h2 * dav + a * Bv.z;
    h3 = h3 * dav + a * Bv.w;
    float yp = h0 * Cv.x + h1 * Cv.y + h2 * Cv.z + h3 * Cv.w;
    yp += __shfl_xor(yp, 1, 64);
    yp += __shfl_xor(yp, 2, 64);
    yp += __shfl_xor(yp, 4, 64);
    yp += __shfl_xor(yp, 8, 64);
    if (ng == 0) yb[(size_t)l * DIN] = yp + Dh * xv;
  }
}

// ---------------- gated RMS norm over one chunk; z is chunk-local [6272][768] ----------------
__global__ __launch_bounds__(256) void gate_rms_kernel(float* __restrict__ Y,
    const float* __restrict__ Z, const float* __restrict__ mw) {
  int wave = threadIdx.x >> 6, lane = threadIdx.x & 63;
  int row = blockIdx.x * 4 + wave;
  if (row >= CHROWS) return;
  float* y = Y + (size_t)row * DIN;
  const float* z = Z + (size_t)row * DIN;
  float4 g[3];
  float ss = 0.f;
#pragma unroll
  for (int q = 0; q < 3; q++) {
    int c = q * 256 + lane * 4;
    float4 yv = *(const float4*)&y[c];
    float4 zv = *(const float4*)&z[c];
    float4 gv;
    gv.x = yv.x * siluf(zv.x);
    gv.y = yv.y * siluf(zv.y);
    gv.z = yv.z * siluf(zv.z);
    gv.w = yv.w * siluf(zv.w);
    ss += gv.x * gv.x + gv.y * gv.y + gv.z * gv.z + gv.w * gv.w;
    g[q] = gv;
  }
#pragma unroll
  for (int o = 32; o > 0; o >>= 1) ss += __shfl_xor(ss, o, 64);
  float rs = rsqrtf(ss * (1.f / 768.f) + 1e-5f);
#pragma unroll
  for (int q = 0; q < 3; q++) {
    int c = q * 256 + lane * 4;
    float4 m = *(const float4*)&mw[c];
    float4 ov;
    ov.x = g[q].x * rs * m.x;
    ov.y = g[q].y * rs * m.y;
    ov.z = g[q].z * rs * m.z;
    ov.w = g[q].w * rs * m.w;
    *(float4*)&y[c] = ov;
  }
}

// ---------------- attention gate: G = sigmoid(xn @ gate_w + gate_b) ----------------
__global__ __launch_bounds__(256) void attgate_kernel(const float* __restrict__ XN,
    const float* __restrict__ gw, const float* __restrict__ gb, float* __restrict__ G) {
  int wave = threadIdx.x >> 6, lane = threadIdx.x & 63;
  int row = blockIdx.x * 4 + wave;
  if (row >= NROWS) return;
  const float* x = XN + (size_t)row * CDIM;
  float acc[12] = {};
#pragma unroll
  for (int q = 0; q < 6; q++) {
    int k = q * 64 + lane;
    float xv = x[k];
    const float* wr = gw + (size_t)k * 12;
    float4 w0 = *(const float4*)&wr[0];
    float4 w1 = *(const float4*)&wr[4];
    float4 w2 = *(const float4*)&wr[8];
    acc[0] += xv * w0.x; acc[1] += xv * w0.y; acc[2]  += xv * w0.z; acc[3]  += xv * w0.w;
    acc[4] += xv * w1.x; acc[5] += xv * w1.y; acc[6]  += xv * w1.z; acc[7]  += xv * w1.w;
    acc[8] += xv * w2.x; acc[9] += xv * w2.y; acc[10] += xv * w2.z; acc[11] += xv * w2.w;
  }
#pragma unroll
  for (int h = 0; h < 12; h++)
#pragma unroll
    for (int o = 32; o > 0; o >>= 1) acc[h] += __shfl_xor(acc[h], o, 64);
  if (lane == 0) {
#pragma unroll
    for (int h = 0; h < 12; h++) {
      float v = acc[h] + gb[h];
      G[(size_t)row * 12 + h] = 1.f / (1.f + expf(-v));
    }
  }
}

// ---------------- windowed attention, one 2-batch chunk; QKV chunk-local [6272][1152] ----------------
__global__ __launch_bounds__(256) void attn_kernel(const float* __restrict__ QKV,
    const float* __restrict__ G, float* __restrict__ XA, int b0) {
  __shared__ float qs[49 * 32];
  __shared__ float ks[49 * 32];
  __shared__ float vs[49 * 32];
  __shared__ float ps[49 * 49];
  int blk = blockIdx.x;               // 128 windows * 12 heads
  int head = blk % NHA;
  int win = blk / NHA;                // [0,128)
  int bl = win >> 6;                  // chunk-local batch
  int wr = win & 63;
  int wy = wr >> 3, wx = wr & 7;
  int t = threadIdx.x;
  const float scale = 0.17677669529663688f; // 32^-0.5

  for (int e = t; e < 1568; e += 256) {
    int tok = e >> 5, d = e & 31;
    int iy = tok / 7, ix = tok - iy * 7;
    size_t rl = (size_t)bl * L_SEQ + (wy * 7 + iy) * 56 + (wx * 7 + ix);
    const float* qp = QKV + rl * 1152 + head * 32 + d;
    qs[e] = qp[0] * scale;
    ks[e] = qp[384];
    vs[e] = qp[768];
  }
  __syncthreads();
  for (int e = t; e < 2401; e += 256) {
    int qi = e / 49, kj = e - qi * 49;
    const float4* q4 = (const float4*)&qs[qi * 32];
    const float4* k4 = (const float4*)&ks[kj * 32];
    float acc = 0.f;
#pragma unroll
    for (int dd = 0; dd < 8; dd++) {
      float4 a = q4[dd], c = k4[dd];
      acc += a.x * c.x + a.y * c.y + a.z * c.z + a.w * c.w;
    }
    ps[e] = acc;
  }
  __syncthreads();
  if (t < 49) {
    float* pr = &ps[t * 49];
    float m = pr[0];
    for (int j = 1; j < 49; j++) m = fmaxf(m, pr[j]);
    float s = 0.f;
    for (int j = 0; j < 49; j++) { float e2 = expf(pr[j] - m); pr[j] = e2; s += e2; }
    float inv = 1.f / s;
    for (int j = 0; j < 49; j++) pr[j] *= inv;
  }
  __syncthreads();
  for (int e = t; e < 1568; e += 256) {
    int qi = e >> 5, d = e & 31;
    const float* pr = &ps[qi * 49];
    float acc = 0.f;
    for (int j = 0; j < 49; j++) acc += pr[j] * vs[j * 32 + d];
    int iy = qi / 7, ix = qi - iy * 7;
    size_t rg = (size_t)(b0 + bl) * L_SEQ + (wy * 7 + iy) * 56 + (wx * 7 + ix);
    float g = G[rg * 12 + head];
    XA[rg * CDIM + head * 32 + d] = acc * g;
  }
}

// ---------------- host launch ----------------
extern "C" void kernel_launch(void* const* d_in, const int* in_sizes, int n_in,
                              void* d_out, int out_size, void* d_ws, size_t ws_size,
                              hipStream_t stream) {
  const float* x        = (const float*)d_in[0];
  const float* norm1_w  = (const float*)d_in[1];
  const float* norm1_b  = (const float*)d_in[2];
  const float* W_in     = (const float*)d_in[3];
  const float* conv_w   = (const float*)d_in[4];
  const float* conv_b   = (const float*)d_in[5];
  const float* dt_bias  = (const float*)d_in[6];
  const float* A_log    = (const float*)d_in[7];
  const float* Dp       = (const float*)d_in[8];
  const float* mnorm_w  = (const float*)d_in[9];
  const float* W_out    = (const float*)d_in[10];
  const float* qkv_w    = (const float*)d_in[11];
  const float* qkv_b    = (const float*)d_in[12];
  const float* gate_w   = (const float*)d_in[13];
  const float* gate_b   = (const float*)d_in[14];
  const float* proj_w   = (const float*)d_in[15];
  const float* proj_b   = (const float*)d_in[16];
  const float* fusion_w = (const float*)d_in[17];
  const float* fusion_b = (const float*)d_in[18];
  const float* norm2_w  = (const float*)d_in[19];
  const float* norm2_b  = (const float*)d_in[20];
  const float* fc1_w    = (const float*)d_in[21];
  const float* fc1_b    = (const float*)d_in[22];
  const float* fc2_w    = (const float*)d_in[23];
  const float* fc2_b    = (const float*)d_in[24];
  float* OUT = (float*)d_out;

  // Workspace pool: 61,917,184 floats = 236.2 MiB
  float* ws = (float*)d_ws;
  float* A_  = ws;                   // xn / xn2            9,633,792
  float* B_  = A_  + 9633792;        // XC then CAT        22,478,848
  float* C_  = B_  + 22478848;       // chunk scratch       9,633,792
  float* D_  = C_  + 9633792;        // Y then XA          19,267,584
  float* DT_ = D_  + 19267584;       //                       301,056
  float* DA_ = DT_ + 301056;         //                       301,056
  float* G_  = DA_ + 301056;         //                       301,056

  // 1. LN1 -> A_
  ln_kernel<<<6272, 256, 0, stream>>>(x, norm1_w, norm1_b, A_);

  // 2. per-chunk: xBC slice GEMM -> scratch, conv -> XC; dt slice GEMM -> DT
  for (int c = 0; c < NCHUNK; c++) {
    const float* Ac = A_ + (size_t)c * CHROWS * CDIM;
    gemm_k<0, false, false><<<dim3(7, 49), 256, 0, stream>>>(
        Ac, W_in + 768, C_, nullptr, nullptr, 0, CHROWS, CONVD, CDIM, CDIM, DPROJ, CONVD, 0);
    conv_kernel<<<(CHROWS * CONVD + 255) / 256, 256, 0, stream>>>(
        C_, conv_w, conv_b, B_ + (size_t)c * CHROWS * CONVD);
    gemm_k<0, false, false><<<dim3(1, 49), 256, 0, stream>>>(
        Ac, W_in + 1664, DT_ + (size_t)c * CHROWS * NHM, nullptr, nullptr, 0,
        CHROWS, NHM, CDIM, CDIM, DPROJ, NHM, 0);
  }

  // 3. dt prep (in place)
  dtprep_kernel<<<(NROWS * NHM + 255) / 256, 256, 0, stream>>>(DT_, dt_bias, A_log, DA_);

  // 4. SSM scan (full): XC(B_) -> Y(D_)
  scan_kernel<<<NBATCH * NHM * 4, 256, 0, stream>>>(B_, DT_, DA_, Dp, D_);

  // 5. per-chunk: z slice GEMM -> scratch, gated RMS norm in-place on Y
  for (int c = 0; c < NCHUNK; c++) {
    const float* Ac = A_ + (size_t)c * CHROWS * CDIM;
    gemm_k<0, false, false><<<dim3(6, 49), 256, 0, stream>>>(
        Ac, W_in, C_, nullptr, nullptr, 0, CHROWS, DIN, CDIM, CDIM, DPROJ, DIN, 0);
    gate_rms_kernel<<<1568, 256, 0, stream>>>(D_ + (size_t)c * CHROWS * DIN, C_, mnorm_w);
  }

  // 6. out_proj: Y @ W_out -> CAT[:, :384] (B_ region, ldc=768)
  gemm_k<0, false, false><<<dim3(3, 196), 256, 0, stream>>>(
      D_, W_out, B_, nullptr, nullptr, 0, NROWS, CDIM, DIN, DIN, CDIM, 2 * CDIM, 0);

  // 7. attention gate (full)
  attgate_kernel<<<6272, 256, 0, stream>>>(A_, gate_w, gate_b, G_);

  // 8. per-chunk: qkv GEMM -> scratch, windowed attention -> XA (D_ region, ld=384)
  for (int c = 0; c < NCHUNK; c++) {
    const float* Ac = A_ + (size_t)c * CHROWS * CDIM;
    gemm_k<0, true, false><<<dim3(9, 49), 256, 0, stream>>>(
        Ac, qkv_w, C_, qkv_b, nullptr, 0, CHROWS, 3 * CDIM, CDIM, CDIM, 3 * CDIM, 3 * CDIM, 0);
    attn_kernel<<<128 * NHA, 256, 0, stream>>>(C_, G_, D_, c * 2);
  }

  // 9. proj: XA @ proj_w -> CAT[:, 384:]
  gemm_k<0, true, false><<<dim3(3, 196), 256, 0, stream>>>(
      D_, proj_w, B_, proj_b, nullptr, 0, NROWS, CDIM, CDIM, CDIM, CDIM, 2 * CDIM, CDIM);

  // 10. fusion + shortcut -> OUT
  gemm_k<0, true, true><<<dim3(3, 196), 256, 0, stream>>>(
      B_, fusion_w, OUT, fusion_b, x, CDIM, NROWS, CDIM, 2 * CDIM, 2 * CDIM, CDIM, CDIM, 0);

  // 11. LN2: OUT -> A_
  ln_kernel<<<6272, 256, 0, stream>>>(OUT, norm2_w, norm2_b, A_);

  // 12. per-chunk MLP: fc1+GELU -> scratch, fc2 + residual (in-place on OUT rows)
  for (int c = 0; c < NCHUNK; c++) {
    const float* Ac = A_ + (size_t)c * CHROWS * CDIM;
    float* Oc = OUT + (size_t)c * CHROWS * CDIM;
    gemm_k<1, true, false><<<dim3(12, 49), 256, 0, stream>>>(
        Ac, fc1_w, C_, fc1_b, nullptr, 0, CHROWS, 4 * CDIM, CDIM, CDIM, 4 * CDIM, 4 * CDIM, 0);
    gemm_k<0, true, true><<<dim3(3, 49), 256, 0, stream>>>(
        C_, fc2_w, Oc, fc2_b, Oc, CDIM, CHROWS, CDIM, 4 * CDIM, 4 * CDIM, CDIM, CDIM, 0);
  }
}

// Round 5
// 1756.221 us; speedup vs baseline: 3.0630x; 3.0630x over previous
//
#include <hip/hip_runtime.h>
#include <math.h>

static constexpr int L_SEQ  = 3136;
static constexpr int NBATCH = 8;
static constexpr int CDIM   = 384;
static constexpr int DIN    = 768;
static constexpr int NHM    = 12;
static constexpr int HDM    = 64;
static constexpr int DPROJ  = 1676;   // 2*768 + 2*64 + 12
static constexpr int CONVD  = 896;    // 768 + 128
static constexpr int NROWS  = NBATCH * L_SEQ; // 25088
static constexpr int NHA    = 12;
static constexpr int CHROWS = 6272;   // 2 batches per chunk (49 * 128)
static constexpr int NCHUNK = 4;
static constexpr int NSEG   = 28;     // scan segments
static constexpr int SEGLEN = 112;    // 3136 / 28

typedef __attribute__((ext_vector_type(8))) short short8;
typedef __attribute__((ext_vector_type(4))) float f32x4;

__device__ __forceinline__ float siluf(float x) { return x / (1.f + __expf(-x)); }
__device__ __forceinline__ unsigned short f2bf(float f) {
  unsigned int u = __float_as_uint(f);
  u += 0x7fff + ((u >> 16) & 1);
  return (unsigned short)(u >> 16);
}
__device__ __forceinline__ float bf2f(unsigned short h) {
  return __uint_as_float(((unsigned int)h) << 16);
}

// ---------------- LayerNorm: one wave per row, C=384, bf16 out ----------------
__global__ __launch_bounds__(256) void ln_kernel(const float* __restrict__ in,
    const float* __restrict__ w, const float* __restrict__ b, unsigned short* __restrict__ out) {
  int wave = threadIdx.x >> 6, lane = threadIdx.x & 63;
  int row = blockIdx.x * 4 + wave;
  if (row >= NROWS) return;
  const float* r = in + (size_t)row * CDIM;
  float2 v[3];
  float s1 = 0.f, s2 = 0.f;
#pragma unroll
  for (int q = 0; q < 3; q++) {
    v[q] = *(const float2*)&r[q * 128 + lane * 2];
    s1 += v[q].x + v[q].y;
    s2 += v[q].x * v[q].x + v[q].y * v[q].y;
  }
#pragma unroll
  for (int o = 32; o > 0; o >>= 1) { s1 += __shfl_xor(s1, o, 64); s2 += __shfl_xor(s2, o, 64); }
  float mu = s1 * (1.f / 384.f);
  float var = s2 * (1.f / 384.f) - mu * mu;
  float rs = rsqrtf(var + 1e-5f);
  unsigned short* o = out + (size_t)row * CDIM;
#pragma unroll
  for (int q = 0; q < 3; q++) {
    int c = q * 128 + lane * 2;
    float2 wv = *(const float2*)&w[c];
    float2 bv = *(const float2*)&b[c];
    float ox = (v[q].x - mu) * rs * wv.x + bv.x;
    float oy = (v[q].y - mu) * rs * wv.y + bv.y;
    unsigned int pk = (unsigned int)f2bf(ox) | ((unsigned int)f2bf(oy) << 16);
    *(unsigned int*)&o[c] = pk;
  }
}

// ---------------- weight convert + transpose: W[K][N] fp32 -> WT[Np][K] bf16 ----------------
// grid (K/32, Np/32), block 256 (32x8). K % 32 == 0. Rows n >= N are zero-filled.
__global__ __launch_bounds__(256) void wconv_kernel(const float* __restrict__ W,
    unsigned short* __restrict__ WT, int K, int N, int ldw) {
  __shared__ float tile[32][33];
  int k0 = blockIdx.x * 32, n0 = blockIdx.y * 32;
  int tx = threadIdx.x & 31, ty = threadIdx.x >> 5;
#pragma unroll
  for (int j = 0; j < 4; j++) {
    int k = k0 + ty + j * 8;
    int n = n0 + tx;
    tile[ty + j * 8][tx] = (n < N) ? W[(size_t)k * ldw + n] : 0.f;
  }
  __syncthreads();
#pragma unroll
  for (int j = 0; j < 4; j++) {
    int n = n0 + ty + j * 8;
    int k = k0 + tx;
    WT[(size_t)n * K + k] = f2bf(tile[tx][ty + j * 8]);
  }
}

// ---------------- bf16 MFMA GEMM: C[m, coff+n] = act(A@W + bias) + res ----------------
// A: M x K bf16 row-major (lda). WT: Np x K bf16 row-major (W transposed, zero-padded).
// 128x128 tile, BK=32, 4 waves, each wave 64x64 via 4x4 grid of 16x16x32 MFMA.
// M % 128 == 0, K % 32 == 0.
template<int ACT, bool HASBIAS, bool HASRES, bool OUTBF>
__global__ __launch_bounds__(256) void gemm_bf(
    const unsigned short* __restrict__ A, const unsigned short* __restrict__ WT,
    void* __restrict__ Cp, const float* __restrict__ bias,
    const float* __restrict__ res, int ldr,
    int M, int N, int K, int lda, int ldc, int coff)
{
  __shared__ unsigned short As[128][40];  // 32 + 8 pad
  __shared__ unsigned short Ws[128][40];
  int t = threadIdx.x;
  int m0 = blockIdx.y * 128, n0 = blockIdx.x * 128;
  int lane = t & 63, w = t >> 6;
  int wr = (w >> 1) * 64, wc = (w & 1) * 64;
  int fl = lane & 15, kq = lane >> 4;
  f32x4 acc[4][4];
#pragma unroll
  for (int i = 0; i < 4; i++)
#pragma unroll
    for (int j = 0; j < 4; j++) acc[i][j] = (f32x4)0.f;

  for (int k0 = 0; k0 < K; k0 += 32) {
#pragma unroll
    for (int i = 0; i < 2; i++) {
      int c = t * 2 + i;          // 0..511
      int row = c >> 2, q = c & 3;
      *(uint4*)&As[row][q * 8] = *(const uint4*)&A[(size_t)(m0 + row) * lda + k0 + q * 8];
      *(uint4*)&Ws[row][q * 8] = *(const uint4*)&WT[(size_t)(n0 + row) * K + k0 + q * 8];
    }
    __syncthreads();
    short8 af[4], bfr[4];
#pragma unroll
    for (int mi = 0; mi < 4; mi++) af[mi] = *(const short8*)&As[wr + mi * 16 + fl][kq * 8];
#pragma unroll
    for (int ni = 0; ni < 4; ni++) bfr[ni] = *(const short8*)&Ws[wc + ni * 16 + fl][kq * 8];
#pragma unroll
    for (int mi = 0; mi < 4; mi++)
#pragma unroll
      for (int ni = 0; ni < 4; ni++)
        acc[mi][ni] = __builtin_amdgcn_mfma_f32_16x16x32_bf16(af[mi], bfr[ni], acc[mi][ni], 0, 0, 0);
    __syncthreads();
  }
  // epilogue: D row = (lane>>4)*4 + r, col = lane&15
  int rbase = (lane >> 4) * 4, cl = lane & 15;
#pragma unroll
  for (int mi = 0; mi < 4; mi++) {
#pragma unroll
    for (int ni = 0; ni < 4; ni++) {
      int n = n0 + wc + ni * 16 + cl;
      if (n >= N) continue;
#pragma unroll
      for (int r = 0; r < 4; r++) {
        int m = m0 + wr + mi * 16 + rbase + r;
        float v = acc[mi][ni][r];
        if (HASBIAS) v += bias[n];
        if (ACT == 1) v = 0.5f * v * (1.f + erff(v * 0.70710678118654752f));
        if (HASRES) v += res[(size_t)m * ldr + n];
        if (OUTBF) ((unsigned short*)Cp)[(size_t)m * ldc + coff + n] = f2bf(v);
        else       ((float*)Cp)[(size_t)m * ldc + coff + n] = v;
      }
    }
  }
}

// ---------------- dt prep (in-place) ----------------
__global__ void dtprep_kernel(float* __restrict__ DT, const float* __restrict__ dt_bias,
    const float* __restrict__ A_log, float* __restrict__ DA) {
  int idx = blockIdx.x * blockDim.x + threadIdx.x;
  if (idx >= NROWS * NHM) return;
  int h = idx % NHM;
  float v = DT[idx] + dt_bias[h];
  float sp = (v > 20.f) ? v : log1pf(expf(v));
  DT[idx] = sp;
  DA[idx] = expf(-expf(A_log[h]) * sp);
}

// ---------------- depthwise causal conv (k=4) + bias + silu; one 2-batch chunk ----------------
__global__ void conv_kernel(const float* __restrict__ xbc, const float* __restrict__ cw,
    const float* __restrict__ cb, float* __restrict__ XC) {
  int idx = blockIdx.x * blockDim.x + threadIdx.x;
  if (idx >= CHROWS * CONVD) return;
  int c = idx % CONVD;
  int row = idx / CONVD;
  int l = row % L_SEQ;
  float acc = cb[c];
#pragma unroll
  for (int j = 0; j < 4; j++) {
    int ls = l - 3 + j;
    if (ls >= 0) acc += xbc[(size_t)(row - 3 + j) * CONVD + c] * cw[c * 4 + j];
  }
  XC[(size_t)row * CONVD + c] = siluf(acc);
}

// ---------------- scan pass 1: per-segment local state + dA product ----------------
// grid (NSEG, 96, 4), block 256: thread p = ps*16 + (t>>4), n = (t&15)*4 .. +4
__global__ __launch_bounds__(256) void scan1_kernel(const float* __restrict__ XC,
    const float* __restrict__ dtp, const float* __restrict__ dAv,
    float* __restrict__ H, float* __restrict__ QS) {
  int seg = blockIdx.x, bh = blockIdx.y, ps = blockIdx.z;
  int b = bh / NHM, head = bh - b * NHM;
  int t = threadIdx.x;
  int pl = t >> 4, ng = t & 15;
  int p = ps * 16 + pl, n0 = ng * 4;
  float h0 = 0.f, h1 = 0.f, h2 = 0.f, h3 = 0.f, q = 1.f;
  int l0 = seg * SEGLEN;
  const float* xcb = XC + ((size_t)b * L_SEQ + l0) * CONVD;
  const float* dtb = dtp + ((size_t)b * L_SEQ + l0) * NHM + head;
  const float* dab = dAv + ((size_t)b * L_SEQ + l0) * NHM + head;
  int xcol = head * HDM + p;
  for (int i = 0; i < SEGLEN; i++) {
    const float* rowp = xcb + (size_t)i * CONVD;
    float xv = rowp[xcol];
    float4 Bv = *(const float4*)&rowp[768 + n0];
    float dtv = dtb[(size_t)i * NHM];
    float dav = dab[(size_t)i * NHM];
    float a = dtv * xv;
    h0 = h0 * dav + a * Bv.x;
    h1 = h1 * dav + a * Bv.y;
    h2 = h2 * dav + a * Bv.z;
    h3 = h3 * dav + a * Bv.w;
    q *= dav;
  }
  float* Hp = H + ((size_t)bh * NSEG + seg) * 4096;
  *(float4*)&Hp[p * 64 + n0] = make_float4(h0, h1, h2, h3);
  if (t == 0) QS[bh * NSEG + seg] = q;
}

// ---------------- scan combine: prefix over segments, in place (H_s -> h_in_s) ----------------
__global__ __launch_bounds__(256) void scomb_kernel(float* __restrict__ H,
    const float* __restrict__ QS) {
  int bh = blockIdx.x;
  int e0 = threadIdx.x * 16;
  float4 cur[4] = {make_float4(0,0,0,0), make_float4(0,0,0,0),
                   make_float4(0,0,0,0), make_float4(0,0,0,0)};
  for (int s = 0; s < NSEG; s++) {
    float* Hp = H + ((size_t)bh * NSEG + s) * 4096 + e0;
    float q = QS[bh * NSEG + s];
#pragma unroll
    for (int i = 0; i < 4; i++) {
      float4 tmp = *(float4*)&Hp[i * 4];
      *(float4*)&Hp[i * 4] = cur[i];
      cur[i].x = q * cur[i].x + tmp.x;
      cur[i].y = q * cur[i].y + tmp.y;
      cur[i].z = q * cur[i].z + tmp.z;
      cur[i].w = q * cur[i].w + tmp.w;
    }
  }
}

// ---------------- scan pass 2: recompute from h_in, emit y (bf16) ----------------
__global__ __launch_bounds__(256) void scan2_kernel(const float* __restrict__ XC,
    const float* __restrict__ dtp, const float* __restrict__ dAv,
    const float* __restrict__ H, const float* __restrict__ Dp,
    unsigned short* __restrict__ Ybf) {
  int seg = blockIdx.x, bh = blockIdx.y, ps = blockIdx.z;
  int b = bh / NHM, head = bh - b * NHM;
  int t = threadIdx.x;
  int pl = t >> 4, ng = t & 15;
  int p = ps * 16 + pl, n0 = ng * 4;
  const float* Hp = H + ((size_t)bh * NSEG + seg) * 4096;
  float4 h4 = *(const float4*)&Hp[p * 64 + n0];
  float h0 = h4.x, h1 = h4.y, h2 = h4.z, h3 = h4.w;
  float Dh = Dp[head];
  int l0 = seg * SEGLEN;
  const float* xcb = XC + ((size_t)b * L_SEQ + l0) * CONVD;
  const float* dtb = dtp + ((size_t)b * L_SEQ + l0) * NHM + head;
  const float* dab = dAv + ((size_t)b * L_SEQ + l0) * NHM + head;
  unsigned short* yb = Ybf + ((size_t)b * L_SEQ + l0) * DIN + head * HDM + p;
  int xcol = head * HDM + p;
  for (int i = 0; i < SEGLEN; i++) {
    const float* rowp = xcb + (size_t)i * CONVD;
    float xv = rowp[xcol];
    float4 Bv = *(const float4*)&rowp[768 + n0];
    float4 Cv = *(const float4*)&rowp[832 + n0];
    float dtv = dtb[(size_t)i * NHM];
    float dav = dab[(size_t)i * NHM];
    float a = dtv * xv;
    h0 = h0 * dav + a * Bv.x;
    h1 = h1 * dav + a * Bv.y;
    h2 = h2 * dav + a * Bv.z;
    h3 = h3 * dav + a * Bv.w;
    float yp = h0 * Cv.x + h1 * Cv.y + h2 * Cv.z + h3 * Cv.w;
    yp += __shfl_xor(yp, 1, 64);
    yp += __shfl_xor(yp, 2, 64);
    yp += __shfl_xor(yp, 4, 64);
    yp += __shfl_xor(yp, 8, 64);
    if (ng == 0) yb[(size_t)i * DIN] = f2bf(yp + Dh * xv);
  }
}

// ---------------- gated RMS norm, one chunk; Y bf16 in-place, z fp32 chunk-local ----------------
__global__ __launch_bounds__(256) void gate_rms_kernel(unsigned short* __restrict__ Y,
    const float* __restrict__ Z, const float* __restrict__ mw) {
  int wave = threadIdx.x >> 6, lane = threadIdx.x & 63;
  int row = blockIdx.x * 4 + wave;
  if (row >= CHROWS) return;
  unsigned short* y = Y + (size_t)row * DIN;
  const float* z = Z + (size_t)row * DIN;
  float g[12];
  float ss = 0.f;
#pragma unroll
  for (int q = 0; q < 3; q++) {
    int c = q * 256 + lane * 4;
    uint2 yu = *(const uint2*)&y[c];
    float4 zv = *(const float4*)&z[c];
    float y0 = bf2f((unsigned short)(yu.x & 0xffff));
    float y1 = bf2f((unsigned short)(yu.x >> 16));
    float y2 = bf2f((unsigned short)(yu.y & 0xffff));
    float y3 = bf2f((unsigned short)(yu.y >> 16));
    float g0 = y0 * siluf(zv.x), g1 = y1 * siluf(zv.y);
    float g2 = y2 * siluf(zv.z), g3 = y3 * siluf(zv.w);
    ss += g0 * g0 + g1 * g1 + g2 * g2 + g3 * g3;
    g[q * 4 + 0] = g0; g[q * 4 + 1] = g1; g[q * 4 + 2] = g2; g[q * 4 + 3] = g3;
  }
#pragma unroll
  for (int o = 32; o > 0; o >>= 1) ss += __shfl_xor(ss, o, 64);
  float rs = rsqrtf(ss * (1.f / 768.f) + 1e-5f);
#pragma unroll
  for (int q = 0; q < 3; q++) {
    int c = q * 256 + lane * 4;
    float4 m = *(const float4*)&mw[c];
    unsigned int lo = (unsigned int)f2bf(g[q*4+0] * rs * m.x) | ((unsigned int)f2bf(g[q*4+1] * rs * m.y) << 16);
    unsigned int hi = (unsigned int)f2bf(g[q*4+2] * rs * m.z) | ((unsigned int)f2bf(g[q*4+3] * rs * m.w) << 16);
    uint2 pk; pk.x = lo; pk.y = hi;
    *(uint2*)&y[c] = pk;
  }
}

// ---------------- attention gate: G = sigmoid(xn @ gate_w + gate_b), xn bf16 ----------------
__global__ __launch_bounds__(256) void attgate_kernel(const unsigned short* __restrict__ XN,
    const float* __restrict__ gw, const float* __restrict__ gb, float* __restrict__ G) {
  int wave = threadIdx.x >> 6, lane = threadIdx.x & 63;
  int row = blockIdx.x * 4 + wave;
  if (row >= NROWS) return;
  const unsigned short* x = XN + (size_t)row * CDIM;
  float acc[12] = {};
#pragma unroll
  for (int q = 0; q < 6; q++) {
    int k = q * 64 + lane;
    float xv = bf2f(x[k]);
    const float* wr = gw + (size_t)k * 12;
    float4 w0 = *(const float4*)&wr[0];
    float4 w1 = *(const float4*)&wr[4];
    float4 w2 = *(const float4*)&wr[8];
    acc[0] += xv * w0.x; acc[1] += xv * w0.y; acc[2]  += xv * w0.z; acc[3]  += xv * w0.w;
    acc[4] += xv * w1.x; acc[5] += xv * w1.y; acc[6]  += xv * w1.z; acc[7]  += xv * w1.w;
    acc[8] += xv * w2.x; acc[9] += xv * w2.y; acc[10] += xv * w2.z; acc[11] += xv * w2.w;
  }
#pragma unroll
  for (int h = 0; h < 12; h++)
#pragma unroll
    for (int o = 32; o > 0; o >>= 1) acc[h] += __shfl_xor(acc[h], o, 64);
  if (lane == 0) {
#pragma unroll
    for (int h = 0; h < 12; h++) {
      float v = acc[h] + gb[h];
      G[(size_t)row * 12 + h] = 1.f / (1.f + expf(-v));
    }
  }
}

// ---------------- windowed attention, one 2-batch chunk; qkv fp32, XA bf16 out ----------------
__global__ __launch_bounds__(256) void attn_kernel(const float* __restrict__ QKV,
    const float* __restrict__ G, unsigned short* __restrict__ XA, int b0) {
  __shared__ float qs[49 * 32];
  __shared__ float ks[49 * 32];
  __shared__ float vs[49 * 32];
  __shared__ float ps[49 * 49];
  int blk = blockIdx.x;
  int head = blk % NHA;
  int win = blk / NHA;
  int bl = win >> 6;
  int wr = win & 63;
  int wy = wr >> 3, wx = wr & 7;
  int t = threadIdx.x;
  const float scale = 0.17677669529663688f;

  for (int e = t; e < 1568; e += 256) {
    int tok = e >> 5, d = e & 31;
    int iy = tok / 7, ix = tok - iy * 7;
    size_t rl = (size_t)bl * L_SEQ + (wy * 7 + iy) * 56 + (wx * 7 + ix);
    const float* qp = QKV + rl * 1152 + head * 32 + d;
    qs[e] = qp[0] * scale;
    ks[e] = qp[384];
    vs[e] = qp[768];
  }
  __syncthreads();
  for (int e = t; e < 2401; e += 256) {
    int qi = e / 49, kj = e - qi * 49;
    const float4* q4 = (const float4*)&qs[qi * 32];
    const float4* k4 = (const float4*)&ks[kj * 32];
    float acc = 0.f;
#pragma unroll
    for (int dd = 0; dd < 8; dd++) {
      float4 a = q4[dd], c = k4[dd];
      acc += a.x * c.x + a.y * c.y + a.z * c.z + a.w * c.w;
    }
    ps[e] = acc;
  }
  __syncthreads();
  if (t < 49) {
    float* pr = &ps[t * 49];
    float m = pr[0];
    for (int j = 1; j < 49; j++) m = fmaxf(m, pr[j]);
    float s = 0.f;
    for (int j = 0; j < 49; j++) { float e2 = expf(pr[j] - m); pr[j] = e2; s += e2; }
    float inv = 1.f / s;
    for (int j = 0; j < 49; j++) pr[j] *= inv;
  }
  __syncthreads();
  for (int e = t; e < 1568; e += 256) {
    int qi = e >> 5, d = e & 31;
    const float* pr = &ps[qi * 49];
    float acc = 0.f;
    for (int j = 0; j < 49; j++) acc += pr[j] * vs[j * 32 + d];
    int iy = qi / 7, ix = qi - iy * 7;
    size_t rg = (size_t)(b0 + bl) * L_SEQ + (wy * 7 + iy) * 56 + (wx * 7 + ix);
    float g = G[rg * 12 + head];
    XA[rg * CDIM + head * 32 + d] = f2bf(acc * g);
  }
}

// ---------------- host launch ----------------
extern "C" void kernel_launch(void* const* d_in, const int* in_sizes, int n_in,
                              void* d_out, int out_size, void* d_ws, size_t ws_size,
                              hipStream_t stream) {
  const float* x        = (const float*)d_in[0];
  const float* norm1_w  = (const float*)d_in[1];
  const float* norm1_b  = (const float*)d_in[2];
  const float* W_in     = (const float*)d_in[3];
  const float* conv_w   = (const float*)d_in[4];
  const float* conv_b   = (const float*)d_in[5];
  const float* dt_bias  = (const float*)d_in[6];
  const float* A_log    = (const float*)d_in[7];
  const float* Dp       = (const float*)d_in[8];
  const float* mnorm_w  = (const float*)d_in[9];
  const float* W_out    = (const float*)d_in[10];
  const float* qkv_w    = (const float*)d_in[11];
  const float* qkv_b    = (const float*)d_in[12];
  const float* gate_w   = (const float*)d_in[13];
  const float* gate_b   = (const float*)d_in[14];
  const float* proj_w   = (const float*)d_in[15];
  const float* proj_b   = (const float*)d_in[16];
  const float* fusion_w = (const float*)d_in[17];
  const float* fusion_b = (const float*)d_in[18];
  const float* norm2_w  = (const float*)d_in[19];
  const float* norm2_b  = (const float*)d_in[20];
  const float* fc1_w    = (const float*)d_in[21];
  const float* fc1_b    = (const float*)d_in[22];
  const float* fc2_w    = (const float*)d_in[23];
  const float* fc2_b    = (const float*)d_in[24];
  float* OUT = (float*)d_out;

  // Workspace pool (floats): total ~50.4M fl = 202 MB
  float* ws = (float*)d_ws;
  unsigned short* XNBF = (unsigned short*)ws;        // 25088x384 bf16  (4,816,896 fl)
  float* B_  = ws + 4816896;                         // XC fp32 / CATbf+XAbf (22,478,848 fl)
  float* C_  = B_ + 22478848;                        // chunk scratch / H     (11,018,240 fl)
  unsigned short* YBF = (unsigned short*)(C_ + 11018240); // 25088x768 bf16  (9,633,792 fl)
  unsigned short* WT  = (unsigned short*)(C_ + 11018240 + 9633792); // 3,047,424 bf16 (1,523,712 fl)
  float* DT_ = (float*)(WT + 3047424);               // 301,056
  float* DA_ = DT_ + 301056;
  float* G_  = DA_ + 301056;
  float* QS_ = G_  + 301056;                         // 2,688
  float* H_  = C_;                                   // 8*12*28*4096 = 11,010,048 fl

  unsigned short* CATBF = (unsigned short*)B_;              // 25088x768 bf16
  unsigned short* XABF  = (unsigned short*)(B_ + 9633792);  // 25088x384 bf16

  // WT sub-buffers (bf16 offsets)
  unsigned short* wt_xbc  = WT;            // 896x384
  unsigned short* wt_dt   = WT + 344064;   // 128x384
  unsigned short* wt_z    = WT + 393216;   // 768x384
  unsigned short* wt_out  = WT + 688128;   // 384x768
  unsigned short* wt_qkv  = WT + 983040;   // 1152x384
  unsigned short* wt_proj = WT + 1425408;  // 384x384
  unsigned short* wt_fus  = WT + 1572864;  // 384x768
  unsigned short* wt_fc1  = WT + 1867776;  // 1536x384
  unsigned short* wt_fc2  = WT + 2457600;  // 384x1536

  // 0. weight convert+transpose (bf16)
  wconv_kernel<<<dim3(12,  28), 256, 0, stream>>>(W_in + 768,  wt_xbc,  384,  896, DPROJ);
  wconv_kernel<<<dim3(12,   4), 256, 0, stream>>>(W_in + 1664, wt_dt,   384,   12, DPROJ);
  wconv_kernel<<<dim3(12,  24), 256, 0, stream>>>(W_in,        wt_z,    384,  768, DPROJ);
  wconv_kernel<<<dim3(24,  12), 256, 0, stream>>>(W_out,       wt_out,  768,  384, 384);
  wconv_kernel<<<dim3(12,  36), 256, 0, stream>>>(qkv_w,       wt_qkv,  384, 1152, 1152);
  wconv_kernel<<<dim3(12,  12), 256, 0, stream>>>(proj_w,      wt_proj, 384,  384, 384);
  wconv_kernel<<<dim3(24,  12), 256, 0, stream>>>(fusion_w,    wt_fus,  768,  384, 384);
  wconv_kernel<<<dim3(12,  48), 256, 0, stream>>>(fc1_w,       wt_fc1,  384, 1536, 1536);
  wconv_kernel<<<dim3(48,  12), 256, 0, stream>>>(fc2_w,       wt_fc2, 1536,  384, 384);

  // 1. LN1 -> XNBF
  ln_kernel<<<6272, 256, 0, stream>>>(x, norm1_w, norm1_b, XNBF);

  // 2. per-chunk: xBC GEMM -> C_, conv -> XC(B_); dt GEMM -> DT
  for (int c = 0; c < NCHUNK; c++) {
    const unsigned short* Ac = XNBF + (size_t)c * CHROWS * CDIM;
    gemm_bf<0, false, false, false><<<dim3(7, 49), 256, 0, stream>>>(
        Ac, wt_xbc, C_, nullptr, nullptr, 0, CHROWS, CONVD, CDIM, CDIM, CONVD, 0);
    conv_kernel<<<(CHROWS * CONVD + 255) / 256, 256, 0, stream>>>(
        C_, conv_w, conv_b, B_ + (size_t)c * CHROWS * CONVD);
    gemm_bf<0, false, false, false><<<dim3(1, 49), 256, 0, stream>>>(
        Ac, wt_dt, DT_ + (size_t)c * CHROWS * NHM, nullptr, nullptr, 0,
        CHROWS, NHM, CDIM, CDIM, NHM, 0);
  }

  // 3. dt prep
  dtprep_kernel<<<(NROWS * NHM + 255) / 256, 256, 0, stream>>>(DT_, dt_bias, A_log, DA_);

  // 4. chunked scan: pass1 -> combine -> pass2 (y bf16 -> YBF)
  scan1_kernel<<<dim3(NSEG, 96, 4), 256, 0, stream>>>(B_, DT_, DA_, H_, QS_);
  scomb_kernel<<<96, 256, 0, stream>>>(H_, QS_);
  scan2_kernel<<<dim3(NSEG, 96, 4), 256, 0, stream>>>(B_, DT_, DA_, H_, Dp, YBF);

  // 5. per-chunk: z GEMM -> C_, gated RMS norm in-place on YBF
  for (int c = 0; c < NCHUNK; c++) {
    const unsigned short* Ac = XNBF + (size_t)c * CHROWS * CDIM;
    gemm_bf<0, false, false, false><<<dim3(6, 49), 256, 0, stream>>>(
        Ac, wt_z, C_, nullptr, nullptr, 0, CHROWS, DIN, CDIM, CDIM, DIN, 0);
    gate_rms_kernel<<<1568, 256, 0, stream>>>(YBF + (size_t)c * CHROWS * DIN, C_, mnorm_w);
  }

  // 6. out_proj: YBF @ wt_out -> CATBF[:, :384]
  gemm_bf<0, false, false, true><<<dim3(3, 196), 256, 0, stream>>>(
      YBF, wt_out, CATBF, nullptr, nullptr, 0, NROWS, CDIM, DIN, DIN, 2 * CDIM, 0);

  // 7. attention gate
  attgate_kernel<<<6272, 256, 0, stream>>>(XNBF, gate_w, gate_b, G_);

  // 8. per-chunk: qkv GEMM -> C_ (fp32), attention -> XABF
  for (int c = 0; c < NCHUNK; c++) {
    const unsigned short* Ac = XNBF + (size_t)c * CHROWS * CDIM;
    gemm_bf<0, true, false, false><<<dim3(9, 49), 256, 0, stream>>>(
        Ac, wt_qkv, C_, qkv_b, nullptr, 0, CHROWS, 3 * CDIM, CDIM, CDIM, 3 * CDIM, 0);
    attn_kernel<<<128 * NHA, 256, 0, stream>>>(C_, G_, XABF, c * 2);
  }

  // 9. proj: XABF @ wt_proj -> CATBF[:, 384:]
  gemm_bf<0, true, false, true><<<dim3(3, 196), 256, 0, stream>>>(
      XABF, wt_proj, CATBF, proj_b, nullptr, 0, NROWS, CDIM, CDIM, CDIM, 2 * CDIM, CDIM);

  // 10. fusion + shortcut -> OUT (fp32)
  gemm_bf<0, true, true, false><<<dim3(3, 196), 256, 0, stream>>>(
      CATBF, wt_fus, OUT, fusion_b, x, CDIM, NROWS, CDIM, 2 * CDIM, 2 * CDIM, CDIM, 0);

  // 11. LN2: OUT -> XNBF
  ln_kernel<<<6272, 256, 0, stream>>>(OUT, norm2_w, norm2_b, XNBF);

  // 12. per-chunk MLP: fc1+GELU -> M1 bf16 (C_), fc2 + residual -> OUT
  for (int c = 0; c < NCHUNK; c++) {
    const unsigned short* Ac = XNBF + (size_t)c * CHROWS * CDIM;
    float* Oc = OUT + (size_t)c * CHROWS * CDIM;
    unsigned short* M1 = (unsigned short*)C_;
    gemm_bf<1, true, false, true><<<dim3(12, 49), 256, 0, stream>>>(
        Ac, wt_fc1, M1, fc1_b, nullptr, 0, CHROWS, 4 * CDIM, CDIM, CDIM, 4 * CDIM, 0);
    gemm_bf<0, true, true, false><<<dim3(3, 49), 256, 0, stream>>>(
        M1, wt_fc2, Oc, fc2_b, Oc, CDIM, CHROWS, CDIM, 4 * CDIM, 4 * CDIM, CDIM, 0);
  }
}

// Round 6
// 1144.682 us; speedup vs baseline: 4.6993x; 1.5342x over previous
//
#include <hip/hip_runtime.h>
#include <math.h>

static constexpr int L_SEQ  = 3136;
static constexpr int NBATCH = 8;
static constexpr int CDIM   = 384;
static constexpr int DIN    = 768;
static constexpr int NHM    = 12;
static constexpr int HDM    = 64;
static constexpr int DPROJ  = 1676;   // 2*768 + 2*64 + 12
static constexpr int CONVD  = 896;    // 768 + 128
static constexpr int NROWS  = NBATCH * L_SEQ; // 25088
static constexpr int NHA    = 12;
static constexpr int NSEG   = 56;     // scan segments
static constexpr int SEGLEN = 56;     // 3136 / 56

typedef __attribute__((ext_vector_type(8))) short short8;
typedef __attribute__((ext_vector_type(4))) float f32x4;

__device__ __forceinline__ float siluf(float x) { return x / (1.f + __expf(-x)); }
__device__ __forceinline__ unsigned short f2bf(float f) {
  unsigned int u = __float_as_uint(f);
  u += 0x7fff + ((u >> 16) & 1);
  return (unsigned short)(u >> 16);
}
__device__ __forceinline__ float bf2f(unsigned short h) {
  return __uint_as_float(((unsigned int)h) << 16);
}

// ---------------- LayerNorm: one wave per row, C=384, bf16 out ----------------
__global__ __launch_bounds__(256) void ln_kernel(const float* __restrict__ in,
    const float* __restrict__ w, const float* __restrict__ b, unsigned short* __restrict__ out) {
  int wave = threadIdx.x >> 6, lane = threadIdx.x & 63;
  int row = blockIdx.x * 4 + wave;
  if (row >= NROWS) return;
  const float* r = in + (size_t)row * CDIM;
  float2 v[3];
  float s1 = 0.f, s2 = 0.f;
#pragma unroll
  for (int q = 0; q < 3; q++) {
    v[q] = *(const float2*)&r[q * 128 + lane * 2];
    s1 += v[q].x + v[q].y;
    s2 += v[q].x * v[q].x + v[q].y * v[q].y;
  }
#pragma unroll
  for (int o = 32; o > 0; o >>= 1) { s1 += __shfl_xor(s1, o, 64); s2 += __shfl_xor(s2, o, 64); }
  float mu = s1 * (1.f / 384.f);
  float var = s2 * (1.f / 384.f) - mu * mu;
  float rs = rsqrtf(var + 1e-5f);
  unsigned short* o = out + (size_t)row * CDIM;
#pragma unroll
  for (int q = 0; q < 3; q++) {
    int c = q * 128 + lane * 2;
    float2 wv = *(const float2*)&w[c];
    float2 bv = *(const float2*)&b[c];
    float ox = (v[q].x - mu) * rs * wv.x + bv.x;
    float oy = (v[q].y - mu) * rs * wv.y + bv.y;
    unsigned int pk = (unsigned int)f2bf(ox) | ((unsigned int)f2bf(oy) << 16);
    *(unsigned int*)&o[c] = pk;
  }
}

// ---------------- weight convert + transpose: W[K][N] fp32 -> WT[Np][K] bf16 ----------------
__global__ __launch_bounds__(256) void wconv_kernel(const float* __restrict__ W,
    unsigned short* __restrict__ WT, int K, int N, int ldw) {
  __shared__ float tile[32][33];
  int k0 = blockIdx.x * 32, n0 = blockIdx.y * 32;
  int tx = threadIdx.x & 31, ty = threadIdx.x >> 5;
#pragma unroll
  for (int j = 0; j < 4; j++) {
    int k = k0 + ty + j * 8;
    int n = n0 + tx;
    tile[ty + j * 8][tx] = (n < N) ? W[(size_t)k * ldw + n] : 0.f;
  }
  __syncthreads();
#pragma unroll
  for (int j = 0; j < 4; j++) {
    int n = n0 + ty + j * 8;
    int k = k0 + tx;
    WT[(size_t)n * K + k] = f2bf(tile[tx][ty + j * 8]);
  }
}

// ---------------- bf16 MFMA GEMM ----------------
template<int ACT, bool HASBIAS, bool HASRES, bool OUTBF>
__global__ __launch_bounds__(256) void gemm_bf(
    const unsigned short* __restrict__ A, const unsigned short* __restrict__ WT,
    void* __restrict__ Cp, const float* __restrict__ bias,
    const float* __restrict__ res, int ldr,
    int M, int N, int K, int lda, int ldc, int coff)
{
  __shared__ unsigned short As[128][40];
  __shared__ unsigned short Ws[128][40];
  int t = threadIdx.x;
  int m0 = blockIdx.y * 128, n0 = blockIdx.x * 128;
  int lane = t & 63, w = t >> 6;
  int wr = (w >> 1) * 64, wc = (w & 1) * 64;
  int fl = lane & 15, kq = lane >> 4;
  f32x4 acc[4][4];
#pragma unroll
  for (int i = 0; i < 4; i++)
#pragma unroll
    for (int j = 0; j < 4; j++) acc[i][j] = (f32x4)0.f;

  for (int k0 = 0; k0 < K; k0 += 32) {
#pragma unroll
    for (int i = 0; i < 2; i++) {
      int c = t * 2 + i;
      int row = c >> 2, q = c & 3;
      *(uint4*)&As[row][q * 8] = *(const uint4*)&A[(size_t)(m0 + row) * lda + k0 + q * 8];
      *(uint4*)&Ws[row][q * 8] = *(const uint4*)&WT[(size_t)(n0 + row) * K + k0 + q * 8];
    }
    __syncthreads();
    short8 af[4], bfr[4];
#pragma unroll
    for (int mi = 0; mi < 4; mi++) af[mi] = *(const short8*)&As[wr + mi * 16 + fl][kq * 8];
#pragma unroll
    for (int ni = 0; ni < 4; ni++) bfr[ni] = *(const short8*)&Ws[wc + ni * 16 + fl][kq * 8];
#pragma unroll
    for (int mi = 0; mi < 4; mi++)
#pragma unroll
      for (int ni = 0; ni < 4; ni++)
        acc[mi][ni] = __builtin_amdgcn_mfma_f32_16x16x32_bf16(af[mi], bfr[ni], acc[mi][ni], 0, 0, 0);
    __syncthreads();
  }
  int rbase = (lane >> 4) * 4, cl = lane & 15;
#pragma unroll
  for (int mi = 0; mi < 4; mi++) {
#pragma unroll
    for (int ni = 0; ni < 4; ni++) {
      int n = n0 + wc + ni * 16 + cl;
      if (n >= N) continue;
#pragma unroll
      for (int r = 0; r < 4; r++) {
        int m = m0 + wr + mi * 16 + rbase + r;
        float v = acc[mi][ni][r];
        if (HASBIAS) v += bias[n];
        if (ACT == 1) v = 0.5f * v * (1.f + erff(v * 0.70710678118654752f));
        if (HASRES) v += res[(size_t)m * ldr + n];
        if (OUTBF) ((unsigned short*)Cp)[(size_t)m * ldc + coff + n] = f2bf(v);
        else       ((float*)Cp)[(size_t)m * ldc + coff + n] = v;
      }
    }
  }
}

// ---------------- dt prep (in-place) ----------------
__global__ void dtprep_kernel(float* __restrict__ DT, const float* __restrict__ dt_bias,
    const float* __restrict__ A_log, float* __restrict__ DA) {
  int idx = blockIdx.x * blockDim.x + threadIdx.x;
  if (idx >= NROWS * NHM) return;
  int h = idx % NHM;
  float v = DT[idx] + dt_bias[h];
  float sp = (v > 20.f) ? v : log1pf(expf(v));
  DT[idx] = sp;
  DA[idx] = expf(-expf(A_log[h]) * sp);
}

// ---------------- depthwise causal conv (k=4) + bias + silu; full ----------------
__global__ void conv_kernel(const float* __restrict__ xbc, const float* __restrict__ cw,
    const float* __restrict__ cb, float* __restrict__ XC) {
  int idx = blockIdx.x * blockDim.x + threadIdx.x;
  if (idx >= NROWS * CONVD) return;
  int c = idx % CONVD;
  int row = idx / CONVD;
  int l = row % L_SEQ;
  float acc = cb[c];
#pragma unroll
  for (int j = 0; j < 4; j++) {
    int ls = l - 3 + j;
    if (ls >= 0) acc += xbc[(size_t)(row - 3 + j) * CONVD + c] * cw[c * 4 + j];
  }
  XC[(size_t)row * CONVD + c] = siluf(acc);
}

// ---------------- scan pass 1: thread owns p, full n-state in registers ----------------
// grid (NSEG, 96), block 64 (one wave). B row is wave-uniform -> scalar loads.
__global__ __launch_bounds__(64) void scan1_kernel(const float* __restrict__ XC,
    const float* __restrict__ dtp, const float* __restrict__ dAv,
    float* __restrict__ H, float* __restrict__ QS) {
  int seg = blockIdx.x, bh = blockIdx.y;
  int b = bh / NHM, head = bh - b * NHM;
  int p = threadIdx.x;
  float h[64];
#pragma unroll
  for (int n = 0; n < 64; n++) h[n] = 0.f;
  float q = 1.f;
  int l0 = seg * SEGLEN;
  const float* xcb = XC + ((size_t)b * L_SEQ + l0) * CONVD;
  const float* dtb = dtp + ((size_t)b * L_SEQ + l0) * NHM + head;
  const float* dab = dAv + ((size_t)b * L_SEQ + l0) * NHM + head;
  int xcol = head * HDM + p;
  for (int i = 0; i < SEGLEN; i++) {
    const float* rowp = xcb + (size_t)i * CONVD;
    float xv = rowp[xcol];
    float dtv = dtb[(size_t)i * NHM];
    float dav = dab[(size_t)i * NHM];
    float a = dtv * xv;
    const float4* B4 = (const float4*)&rowp[768];
#pragma unroll
    for (int nq = 0; nq < 16; nq++) {
      float4 Bq = B4[nq];
      h[nq * 4 + 0] = h[nq * 4 + 0] * dav + a * Bq.x;
      h[nq * 4 + 1] = h[nq * 4 + 1] * dav + a * Bq.y;
      h[nq * 4 + 2] = h[nq * 4 + 2] * dav + a * Bq.z;
      h[nq * 4 + 3] = h[nq * 4 + 3] * dav + a * Bq.w;
    }
    q *= dav;
  }
  float* Hp = H + ((size_t)bh * NSEG + seg) * 4096 + p * 64;
#pragma unroll
  for (int nq = 0; nq < 16; nq++)
    *(float4*)&Hp[nq * 4] = make_float4(h[nq*4], h[nq*4+1], h[nq*4+2], h[nq*4+3]);
  if (p == 0) QS[bh * NSEG + seg] = q;
}

// ---------------- scan combine: prefix over segments (H_s -> h_in_s) ----------------
// grid (96, 16), block 64: thread owns one float4 of the 4096-element state
__global__ __launch_bounds__(64) void scomb_kernel(float* __restrict__ H,
    const float* __restrict__ QS) {
  int bh = blockIdx.x;
  int e = (blockIdx.y * 64 + threadIdx.x) * 4;
  float4 cur = make_float4(0.f, 0.f, 0.f, 0.f);
  for (int s = 0; s < NSEG; s++) {
    float* Hp = H + ((size_t)bh * NSEG + s) * 4096 + e;
    float q = QS[bh * NSEG + s];
    float4 tmp = *(float4*)Hp;
    *(float4*)Hp = cur;
    cur.x = q * cur.x + tmp.x;
    cur.y = q * cur.y + tmp.y;
    cur.z = q * cur.z + tmp.z;
    cur.w = q * cur.w + tmp.w;
  }
}

// ---------------- scan pass 2: recompute from h_in, emit y (bf16), no shuffles ----------------
__global__ __launch_bounds__(64) void scan2_kernel(const float* __restrict__ XC,
    const float* __restrict__ dtp, const float* __restrict__ dAv,
    const float* __restrict__ H, const float* __restrict__ Dp,
    unsigned short* __restrict__ Ybf) {
  int seg = blockIdx.x, bh = blockIdx.y;
  int b = bh / NHM, head = bh - b * NHM;
  int p = threadIdx.x;
  float h[64];
  const float* Hp = H + ((size_t)bh * NSEG + seg) * 4096 + p * 64;
#pragma unroll
  for (int nq = 0; nq < 16; nq++) {
    float4 h4 = *(const float4*)&Hp[nq * 4];
    h[nq*4] = h4.x; h[nq*4+1] = h4.y; h[nq*4+2] = h4.z; h[nq*4+3] = h4.w;
  }
  float Dh = Dp[head];
  int l0 = seg * SEGLEN;
  const float* xcb = XC + ((size_t)b * L_SEQ + l0) * CONVD;
  const float* dtb = dtp + ((size_t)b * L_SEQ + l0) * NHM + head;
  const float* dab = dAv + ((size_t)b * L_SEQ + l0) * NHM + head;
  unsigned short* yb = Ybf + ((size_t)b * L_SEQ + l0) * DIN + head * HDM + p;
  int xcol = head * HDM + p;
  for (int i = 0; i < SEGLEN; i++) {
    const float* rowp = xcb + (size_t)i * CONVD;
    float xv = rowp[xcol];
    float dtv = dtb[(size_t)i * NHM];
    float dav = dab[(size_t)i * NHM];
    float a = dtv * xv;
    const float4* B4 = (const float4*)&rowp[768];
    const float4* C4 = (const float4*)&rowp[832];
    float y0 = 0.f, y1 = 0.f, y2 = 0.f, y3 = 0.f;
#pragma unroll
    for (int nq = 0; nq < 16; nq++) {
      float4 Bq = B4[nq];
      float4 Cq = C4[nq];
      h[nq * 4 + 0] = h[nq * 4 + 0] * dav + a * Bq.x;
      h[nq * 4 + 1] = h[nq * 4 + 1] * dav + a * Bq.y;
      h[nq * 4 + 2] = h[nq * 4 + 2] * dav + a * Bq.z;
      h[nq * 4 + 3] = h[nq * 4 + 3] * dav + a * Bq.w;
      y0 += h[nq * 4 + 0] * Cq.x;
      y1 += h[nq * 4 + 1] * Cq.y;
      y2 += h[nq * 4 + 2] * Cq.z;
      y3 += h[nq * 4 + 3] * Cq.w;
    }
    float yp = (y0 + y1) + (y2 + y3) + Dh * xv;
    yb[(size_t)i * DIN] = f2bf(yp);
  }
}

// ---------------- gated RMS norm (full); Y bf16 in-place, z fp32 ----------------
__global__ __launch_bounds__(256) void gate_rms_kernel(unsigned short* __restrict__ Y,
    const float* __restrict__ Z, const float* __restrict__ mw) {
  int wave = threadIdx.x >> 6, lane = threadIdx.x & 63;
  int row = blockIdx.x * 4 + wave;
  if (row >= NROWS) return;
  unsigned short* y = Y + (size_t)row * DIN;
  const float* z = Z + (size_t)row * DIN;
  float g[12];
  float ss = 0.f;
#pragma unroll
  for (int q = 0; q < 3; q++) {
    int c = q * 256 + lane * 4;
    uint2 yu = *(const uint2*)&y[c];
    float4 zv = *(const float4*)&z[c];
    float y0 = bf2f((unsigned short)(yu.x & 0xffff));
    float y1 = bf2f((unsigned short)(yu.x >> 16));
    float y2 = bf2f((unsigned short)(yu.y & 0xffff));
    float y3 = bf2f((unsigned short)(yu.y >> 16));
    float g0 = y0 * siluf(zv.x), g1 = y1 * siluf(zv.y);
    float g2 = y2 * siluf(zv.z), g3 = y3 * siluf(zv.w);
    ss += g0 * g0 + g1 * g1 + g2 * g2 + g3 * g3;
    g[q * 4 + 0] = g0; g[q * 4 + 1] = g1; g[q * 4 + 2] = g2; g[q * 4 + 3] = g3;
  }
#pragma unroll
  for (int o = 32; o > 0; o >>= 1) ss += __shfl_xor(ss, o, 64);
  float rs = rsqrtf(ss * (1.f / 768.f) + 1e-5f);
#pragma unroll
  for (int q = 0; q < 3; q++) {
    int c = q * 256 + lane * 4;
    float4 m = *(const float4*)&mw[c];
    unsigned int lo = (unsigned int)f2bf(g[q*4+0] * rs * m.x) | ((unsigned int)f2bf(g[q*4+1] * rs * m.y) << 16);
    unsigned int hi = (unsigned int)f2bf(g[q*4+2] * rs * m.z) | ((unsigned int)f2bf(g[q*4+3] * rs * m.w) << 16);
    uint2 pk; pk.x = lo; pk.y = hi;
    *(uint2*)&y[c] = pk;
  }
}

// ---------------- attention gate ----------------
__global__ __launch_bounds__(256) void attgate_kernel(const unsigned short* __restrict__ XN,
    const float* __restrict__ gw, const float* __restrict__ gb, float* __restrict__ G) {
  int wave = threadIdx.x >> 6, lane = threadIdx.x & 63;
  int row = blockIdx.x * 4 + wave;
  if (row >= NROWS) return;
  const unsigned short* x = XN + (size_t)row * CDIM;
  float acc[12] = {};
#pragma unroll
  for (int q = 0; q < 6; q++) {
    int k = q * 64 + lane;
    float xv = bf2f(x[k]);
    const float* wr = gw + (size_t)k * 12;
    float4 w0 = *(const float4*)&wr[0];
    float4 w1 = *(const float4*)&wr[4];
    float4 w2 = *(const float4*)&wr[8];
    acc[0] += xv * w0.x; acc[1] += xv * w0.y; acc[2]  += xv * w0.z; acc[3]  += xv * w0.w;
    acc[4] += xv * w1.x; acc[5] += xv * w1.y; acc[6]  += xv * w1.z; acc[7]  += xv * w1.w;
    acc[8] += xv * w2.x; acc[9] += xv * w2.y; acc[10] += xv * w2.z; acc[11] += xv * w2.w;
  }
#pragma unroll
  for (int h = 0; h < 12; h++)
#pragma unroll
    for (int o = 32; o > 0; o >>= 1) acc[h] += __shfl_xor(acc[h], o, 64);
  if (lane == 0) {
#pragma unroll
    for (int h = 0; h < 12; h++) {
      float v = acc[h] + gb[h];
      G[(size_t)row * 12 + h] = 1.f / (1.f + expf(-v));
    }
  }
}

// ---------------- windowed attention (full batch); qkv bf16, XA bf16 out ----------------
__global__ __launch_bounds__(256) void attn_kernel(const unsigned short* __restrict__ QKV,
    const float* __restrict__ G, unsigned short* __restrict__ XA) {
  __shared__ float qs[49 * 32];
  __shared__ float ks[49 * 32];
  __shared__ float vs[49 * 32];
  __shared__ float ps[49 * 49];
  int blk = blockIdx.x;
  int head = blk % NHA;
  int win = blk / NHA;          // [0, 512)
  int b = win >> 6;
  int wr = win & 63;
  int wy = wr >> 3, wx = wr & 7;
  int t = threadIdx.x;
  const float scale = 0.17677669529663688f;

  for (int e = t; e < 1568; e += 256) {
    int tok = e >> 5, d = e & 31;
    int iy = tok / 7, ix = tok - iy * 7;
    size_t rl = (size_t)b * L_SEQ + (wy * 7 + iy) * 56 + (wx * 7 + ix);
    const unsigned short* qp = QKV + rl * 1152 + head * 32 + d;
    qs[e] = bf2f(qp[0]) * scale;
    ks[e] = bf2f(qp[384]);
    vs[e] = bf2f(qp[768]);
  }
  __syncthreads();
  for (int e = t; e < 2401; e += 256) {
    int qi = e / 49, kj = e - qi * 49;
    const float4* q4 = (const float4*)&qs[qi * 32];
    const float4* k4 = (const float4*)&ks[kj * 32];
    float acc = 0.f;
#pragma unroll
    for (int dd = 0; dd < 8; dd++) {
      float4 a = q4[dd], c = k4[dd];
      acc += a.x * c.x + a.y * c.y + a.z * c.z + a.w * c.w;
    }
    ps[e] = acc;
  }
  __syncthreads();
  if (t < 49) {
    float* pr = &ps[t * 49];
    float m = pr[0];
    for (int j = 1; j < 49; j++) m = fmaxf(m, pr[j]);
    float s = 0.f;
    for (int j = 0; j < 49; j++) { float e2 = expf(pr[j] - m); pr[j] = e2; s += e2; }
    float inv = 1.f / s;
    for (int j = 0; j < 49; j++) pr[j] *= inv;
  }
  __syncthreads();
  for (int e = t; e < 1568; e += 256) {
    int qi = e >> 5, d = e & 31;
    const float* pr = &ps[qi * 49];
    float acc = 0.f;
    for (int j = 0; j < 49; j++) acc += pr[j] * vs[j * 32 + d];
    int iy = qi / 7, ix = qi - iy * 7;
    size_t rg = (size_t)b * L_SEQ + (wy * 7 + iy) * 56 + (wx * 7 + ix);
    float g = G[rg * 12 + head];
    XA[rg * CDIM + head * 32 + d] = f2bf(acc * g);
  }
}

// ---------------- host launch ----------------
extern "C" void kernel_launch(void* const* d_in, const int* in_sizes, int n_in,
                              void* d_out, int out_size, void* d_ws, size_t ws_size,
                              hipStream_t stream) {
  const float* x        = (const float*)d_in[0];
  const float* norm1_w  = (const float*)d_in[1];
  const float* norm1_b  = (const float*)d_in[2];
  const float* W_in     = (const float*)d_in[3];
  const float* conv_w   = (const float*)d_in[4];
  const float* conv_b   = (const float*)d_in[5];
  const float* dt_bias  = (const float*)d_in[6];
  const float* A_log    = (const float*)d_in[7];
  const float* Dp       = (const float*)d_in[8];
  const float* mnorm_w  = (const float*)d_in[9];
  const float* W_out    = (const float*)d_in[10];
  const float* qkv_w    = (const float*)d_in[11];
  const float* qkv_b    = (const float*)d_in[12];
  const float* gate_w   = (const float*)d_in[13];
  const float* gate_b   = (const float*)d_in[14];
  const float* proj_w   = (const float*)d_in[15];
  const float* proj_b   = (const float*)d_in[16];
  const float* fusion_w = (const float*)d_in[17];
  const float* fusion_b = (const float*)d_in[18];
  const float* norm2_w  = (const float*)d_in[19];
  const float* norm2_b  = (const float*)d_in[20];
  const float* fc1_w    = (const float*)d_in[21];
  const float* fc1_b    = (const float*)d_in[22];
  const float* fc2_w    = (const float*)d_in[23];
  const float* fc2_b    = (const float*)d_in[24];
  float* OUT = (float*)d_out;

  // Workspace pool (float units): total 61,837,952 fl = 235.9 MB (round-3-proven size)
  float* ws = (float*)d_ws;
  unsigned short* XNBF = (unsigned short*)ws;              // 25088x384 bf16 (4,816,896 fl)
  float* XC_  = ws + 4816896;                              // XC fp32 full (22,478,848 fl); later CATBF+XABF
  float* SCR  = XC_ + 22478848;                            // xBC fp32 -> H -> z fp32 -> QKVbf -> M1bf (22,478,848 fl)
  unsigned short* YBF = (unsigned short*)(SCR + 22478848); // 25088x768 bf16 (9,633,792 fl)
  unsigned short* WT  = (unsigned short*)(SCR + 22478848 + 9633792); // 3,047,424 bf16
  float* DT_ = (float*)(WT + 3047424);                     // 301,056
  float* DA_ = DT_ + 301056;                               // 301,056
  float* G_  = DA_ + 301056;                               // 301,056
  float* QS_ = G_  + 301056;                               // 5,376

  float* H_ = SCR;                                         // 96*56*4096 = 22,020,096 fl
  float* Zf = SCR;                                         // z fp32 full (19,267,584 fl), after scan2
  unsigned short* QKVBF = (unsigned short*)SCR;            // 25088x1152 bf16, after gate_rms
  unsigned short* M1BF  = (unsigned short*)SCR;            // 25088x1536 bf16, after attn
  unsigned short* CATBF = (unsigned short*)XC_;            // 25088x768 bf16, after scan2
  unsigned short* XABF  = (unsigned short*)(XC_ + 9633792);// 25088x384 bf16

  // WT sub-buffers (bf16 offsets)
  unsigned short* wt_xbc  = WT;            // 896x384
  unsigned short* wt_dt   = WT + 344064;   // 128x384
  unsigned short* wt_z    = WT + 393216;   // 768x384
  unsigned short* wt_out  = WT + 688128;   // 384x768
  unsigned short* wt_qkv  = WT + 983040;   // 1152x384
  unsigned short* wt_proj = WT + 1425408;  // 384x384
  unsigned short* wt_fus  = WT + 1572864;  // 384x768
  unsigned short* wt_fc1  = WT + 1867776;  // 1536x384
  unsigned short* wt_fc2  = WT + 2457600;  // 384x1536

  // 0. weight convert+transpose (bf16)
  wconv_kernel<<<dim3(12,  28), 256, 0, stream>>>(W_in + 768,  wt_xbc,  384,  896, DPROJ);
  wconv_kernel<<<dim3(12,   4), 256, 0, stream>>>(W_in + 1664, wt_dt,   384,   12, DPROJ);
  wconv_kernel<<<dim3(12,  24), 256, 0, stream>>>(W_in,        wt_z,    384,  768, DPROJ);
  wconv_kernel<<<dim3(24,  12), 256, 0, stream>>>(W_out,       wt_out,  768,  384, 384);
  wconv_kernel<<<dim3(12,  36), 256, 0, stream>>>(qkv_w,       wt_qkv,  384, 1152, 1152);
  wconv_kernel<<<dim3(12,  12), 256, 0, stream>>>(proj_w,      wt_proj, 384,  384, 384);
  wconv_kernel<<<dim3(24,  12), 256, 0, stream>>>(fusion_w,    wt_fus,  768,  384, 384);
  wconv_kernel<<<dim3(12,  48), 256, 0, stream>>>(fc1_w,       wt_fc1,  384, 1536, 1536);
  wconv_kernel<<<dim3(48,  12), 256, 0, stream>>>(fc2_w,       wt_fc2, 1536,  384, 384);

  // 1. LN1 -> XNBF
  ln_kernel<<<6272, 256, 0, stream>>>(x, norm1_w, norm1_b, XNBF);

  // 2. xBC GEMM (full) -> SCR; conv -> XC; dt GEMM -> DT
  gemm_bf<0, false, false, false><<<dim3(7, 196), 256, 0, stream>>>(
      XNBF, wt_xbc, SCR, nullptr, nullptr, 0, NROWS, CONVD, CDIM, CDIM, CONVD, 0);
  conv_kernel<<<(NROWS * CONVD + 255) / 256, 256, 0, stream>>>(SCR, conv_w, conv_b, XC_);
  gemm_bf<0, false, false, false><<<dim3(1, 196), 256, 0, stream>>>(
      XNBF, wt_dt, DT_, nullptr, nullptr, 0, NROWS, NHM, CDIM, CDIM, NHM, 0);

  // 3. dt prep
  dtprep_kernel<<<(NROWS * NHM + 255) / 256, 256, 0, stream>>>(DT_, dt_bias, A_log, DA_);

  // 4. chunked scan (register-state, shuffle-free)
  scan1_kernel<<<dim3(NSEG, 96), 64, 0, stream>>>(XC_, DT_, DA_, H_, QS_);
  scomb_kernel<<<dim3(96, 16), 64, 0, stream>>>(H_, QS_);
  scan2_kernel<<<dim3(NSEG, 96), 64, 0, stream>>>(XC_, DT_, DA_, H_, Dp, YBF);

  // 5. z GEMM (full) -> SCR; gated RMS norm in-place on YBF
  gemm_bf<0, false, false, false><<<dim3(6, 196), 256, 0, stream>>>(
      XNBF, wt_z, Zf, nullptr, nullptr, 0, NROWS, DIN, CDIM, CDIM, DIN, 0);
  gate_rms_kernel<<<6272, 256, 0, stream>>>(YBF, Zf, mnorm_w);

  // 6. out_proj: YBF @ wt_out -> CATBF[:, :384]
  gemm_bf<0, false, false, true><<<dim3(3, 196), 256, 0, stream>>>(
      YBF, wt_out, CATBF, nullptr, nullptr, 0, NROWS, CDIM, DIN, DIN, 2 * CDIM, 0);

  // 7. attention gate
  attgate_kernel<<<6272, 256, 0, stream>>>(XNBF, gate_w, gate_b, G_);

  // 8. qkv GEMM (full, bf16 out) -> SCR; attention -> XABF
  gemm_bf<0, true, false, true><<<dim3(9, 196), 256, 0, stream>>>(
      XNBF, wt_qkv, QKVBF, qkv_b, nullptr, 0, NROWS, 3 * CDIM, CDIM, CDIM, 3 * CDIM, 0);
  attn_kernel<<<512 * NHA, 256, 0, stream>>>(QKVBF, G_, XABF);

  // 9. proj: XABF @ wt_proj -> CATBF[:, 384:]
  gemm_bf<0, true, false, true><<<dim3(3, 196), 256, 0, stream>>>(
      XABF, wt_proj, CATBF, proj_b, nullptr, 0, NROWS, CDIM, CDIM, CDIM, 2 * CDIM, CDIM);

  // 10. fusion + shortcut -> OUT (fp32)
  gemm_bf<0, true, true, false><<<dim3(3, 196), 256, 0, stream>>>(
      CATBF, wt_fus, OUT, fusion_b, x, CDIM, NROWS, CDIM, 2 * CDIM, 2 * CDIM, CDIM, 0);

  // 11. LN2: OUT -> XNBF
  ln_kernel<<<6272, 256, 0, stream>>>(OUT, norm2_w, norm2_b, XNBF);

  // 12. MLP: fc1+GELU (full, bf16 out) -> SCR; fc2 + residual -> OUT
  gemm_bf<1, true, false, true><<<dim3(12, 196), 256, 0, stream>>>(
      XNBF, wt_fc1, M1BF, fc1_b, nullptr, 0, NROWS, 4 * CDIM, CDIM, CDIM, 4 * CDIM, 0);
  gemm_bf<0, true, true, false><<<dim3(3, 196), 256, 0, stream>>>(
      M1BF, wt_fc2, OUT, fc2_b, OUT, CDIM, NROWS, CDIM, 4 * CDIM, 4 * CDIM, CDIM, 0);
}

// Round 7
// 1115.780 us; speedup vs baseline: 4.8211x; 1.0259x over previous
//
#include <hip/hip_runtime.h>
#include <math.h>

static constexpr int L_SEQ  = 3136;
static constexpr int NBATCH = 8;
static constexpr int CDIM   = 384;
static constexpr int DIN    = 768;
static constexpr int NHM    = 12;
static constexpr int HDM    = 64;
static constexpr int DPROJ  = 1676;   // 2*768 + 2*64 + 12
static constexpr int CONVD  = 896;    // 768 + 128
static constexpr int NROWS  = NBATCH * L_SEQ; // 25088
static constexpr int NHA    = 12;
static constexpr int NSEG   = 56;     // scan segments
static constexpr int SEGLEN = 56;     // 3136 / 56

typedef __attribute__((ext_vector_type(8))) short short8;
typedef __attribute__((ext_vector_type(4))) float f32x4;

__device__ __forceinline__ float siluf(float x) { return x / (1.f + __expf(-x)); }
__device__ __forceinline__ unsigned short f2bf(float f) {
  unsigned int u = __float_as_uint(f);
  u += 0x7fff + ((u >> 16) & 1);
  return (unsigned short)(u >> 16);
}
__device__ __forceinline__ float bf2f(unsigned short h) {
  return __uint_as_float(((unsigned int)h) << 16);
}

// ---------------- LayerNorm: one wave per row, C=384, bf16 out ----------------
__global__ __launch_bounds__(256) void ln_kernel(const float* __restrict__ in,
    const float* __restrict__ w, const float* __restrict__ b, unsigned short* __restrict__ out) {
  int wave = threadIdx.x >> 6, lane = threadIdx.x & 63;
  int row = blockIdx.x * 4 + wave;
  if (row >= NROWS) return;
  const float* r = in + (size_t)row * CDIM;
  float2 v[3];
  float s1 = 0.f, s2 = 0.f;
#pragma unroll
  for (int q = 0; q < 3; q++) {
    v[q] = *(const float2*)&r[q * 128 + lane * 2];
    s1 += v[q].x + v[q].y;
    s2 += v[q].x * v[q].x + v[q].y * v[q].y;
  }
#pragma unroll
  for (int o = 32; o > 0; o >>= 1) { s1 += __shfl_xor(s1, o, 64); s2 += __shfl_xor(s2, o, 64); }
  float mu = s1 * (1.f / 384.f);
  float var = s2 * (1.f / 384.f) - mu * mu;
  float rs = rsqrtf(var + 1e-5f);
  unsigned short* o = out + (size_t)row * CDIM;
#pragma unroll
  for (int q = 0; q < 3; q++) {
    int c = q * 128 + lane * 2;
    float2 wv = *(const float2*)&w[c];
    float2 bv = *(const float2*)&b[c];
    float ox = (v[q].x - mu) * rs * wv.x + bv.x;
    float oy = (v[q].y - mu) * rs * wv.y + bv.y;
    unsigned int pk = (unsigned int)f2bf(ox) | ((unsigned int)f2bf(oy) << 16);
    *(unsigned int*)&o[c] = pk;
  }
}

// ---------------- weight convert + transpose: W[K][N] fp32 -> WT[Np][K] bf16 ----------------
__global__ __launch_bounds__(256) void wconv_kernel(const float* __restrict__ W,
    unsigned short* __restrict__ WT, int K, int N, int ldw) {
  __shared__ float tile[32][33];
  int k0 = blockIdx.x * 32, n0 = blockIdx.y * 32;
  int tx = threadIdx.x & 31, ty = threadIdx.x >> 5;
#pragma unroll
  for (int j = 0; j < 4; j++) {
    int k = k0 + ty + j * 8;
    int n = n0 + tx;
    tile[ty + j * 8][tx] = (n < N) ? W[(size_t)k * ldw + n] : 0.f;
  }
  __syncthreads();
#pragma unroll
  for (int j = 0; j < 4; j++) {
    int n = n0 + ty + j * 8;
    int k = k0 + tx;
    WT[(size_t)n * K + k] = f2bf(tile[tx][ty + j * 8]);
  }
}

// ---------------- bf16 MFMA GEMM ----------------
template<int ACT, bool HASBIAS, bool HASRES, bool OUTBF>
__global__ __launch_bounds__(256) void gemm_bf(
    const unsigned short* __restrict__ A, const unsigned short* __restrict__ WT,
    void* __restrict__ Cp, const float* __restrict__ bias,
    const float* __restrict__ res, int ldr,
    int M, int N, int K, int lda, int ldc, int coff)
{
  __shared__ unsigned short As[128][40];
  __shared__ unsigned short Ws[128][40];
  int t = threadIdx.x;
  int m0 = blockIdx.y * 128, n0 = blockIdx.x * 128;
  int lane = t & 63, w = t >> 6;
  int wr = (w >> 1) * 64, wc = (w & 1) * 64;
  int fl = lane & 15, kq = lane >> 4;
  f32x4 acc[4][4];
#pragma unroll
  for (int i = 0; i < 4; i++)
#pragma unroll
    for (int j = 0; j < 4; j++) acc[i][j] = (f32x4)0.f;

  for (int k0 = 0; k0 < K; k0 += 32) {
#pragma unroll
    for (int i = 0; i < 2; i++) {
      int c = t * 2 + i;
      int row = c >> 2, q = c & 3;
      *(uint4*)&As[row][q * 8] = *(const uint4*)&A[(size_t)(m0 + row) * lda + k0 + q * 8];
      *(uint4*)&Ws[row][q * 8] = *(const uint4*)&WT[(size_t)(n0 + row) * K + k0 + q * 8];
    }
    __syncthreads();
    short8 af[4], bfr[4];
#pragma unroll
    for (int mi = 0; mi < 4; mi++) af[mi] = *(const short8*)&As[wr + mi * 16 + fl][kq * 8];
#pragma unroll
    for (int ni = 0; ni < 4; ni++) bfr[ni] = *(const short8*)&Ws[wc + ni * 16 + fl][kq * 8];
#pragma unroll
    for (int mi = 0; mi < 4; mi++)
#pragma unroll
      for (int ni = 0; ni < 4; ni++)
        acc[mi][ni] = __builtin_amdgcn_mfma_f32_16x16x32_bf16(af[mi], bfr[ni], acc[mi][ni], 0, 0, 0);
    __syncthreads();
  }
  int rbase = (lane >> 4) * 4, cl = lane & 15;
#pragma unroll
  for (int mi = 0; mi < 4; mi++) {
#pragma unroll
    for (int ni = 0; ni < 4; ni++) {
      int n = n0 + wc + ni * 16 + cl;
      if (n >= N) continue;
#pragma unroll
      for (int r = 0; r < 4; r++) {
        int m = m0 + wr + mi * 16 + rbase + r;
        float v = acc[mi][ni][r];
        if (HASBIAS) v += bias[n];
        if (ACT == 1) v = 0.5f * v * (1.f + erff(v * 0.70710678118654752f));
        if (HASRES) v += res[(size_t)m * ldr + n];
        if (OUTBF) ((unsigned short*)Cp)[(size_t)m * ldc + coff + n] = f2bf(v);
        else       ((float*)Cp)[(size_t)m * ldc + coff + n] = v;
      }
    }
  }
}

// ---------------- dt prep (in-place) ----------------
__global__ void dtprep_kernel(float* __restrict__ DT, const float* __restrict__ dt_bias,
    const float* __restrict__ A_log, float* __restrict__ DA) {
  int idx = blockIdx.x * blockDim.x + threadIdx.x;
  if (idx >= NROWS * NHM) return;
  int h = idx % NHM;
  float v = DT[idx] + dt_bias[h];
  float sp = (v > 20.f) ? v : log1pf(expf(v));
  DT[idx] = sp;
  DA[idx] = expf(-expf(A_log[h]) * sp);
}

// ---------------- depthwise causal conv (k=4) + bias + silu; full ----------------
__global__ void conv_kernel(const float* __restrict__ xbc, const float* __restrict__ cw,
    const float* __restrict__ cb, float* __restrict__ XC) {
  int idx = blockIdx.x * blockDim.x + threadIdx.x;
  if (idx >= NROWS * CONVD) return;
  int c = idx % CONVD;
  int row = idx / CONVD;
  int l = row % L_SEQ;
  float acc = cb[c];
#pragma unroll
  for (int j = 0; j < 4; j++) {
    int ls = l - 3 + j;
    if (ls >= 0) acc += xbc[(size_t)(row - 3 + j) * CONVD + c] * cw[c * 4 + j];
  }
  XC[(size_t)row * CONVD + c] = siluf(acc);
}

// ---------------- scan pass 1: thread owns p, full n-state in registers ----------------
__global__ __launch_bounds__(64) void scan1_kernel(const float* __restrict__ XC,
    const float* __restrict__ dtp, const float* __restrict__ dAv,
    float* __restrict__ H, float* __restrict__ QS) {
  int seg = blockIdx.x, bh = blockIdx.y;
  int b = bh / NHM, head = bh - b * NHM;
  int p = threadIdx.x;
  float h[64];
#pragma unroll
  for (int n = 0; n < 64; n++) h[n] = 0.f;
  float q = 1.f;
  int l0 = seg * SEGLEN;
  const float* xcb = XC + ((size_t)b * L_SEQ + l0) * CONVD;
  const float* dtb = dtp + ((size_t)b * L_SEQ + l0) * NHM + head;
  const float* dab = dAv + ((size_t)b * L_SEQ + l0) * NHM + head;
  int xcol = head * HDM + p;
  for (int i = 0; i < SEGLEN; i++) {
    const float* rowp = xcb + (size_t)i * CONVD;
    float xv = rowp[xcol];
    float dtv = dtb[(size_t)i * NHM];
    float dav = dab[(size_t)i * NHM];
    float a = dtv * xv;
    const float4* B4 = (const float4*)&rowp[768];
#pragma unroll
    for (int nq = 0; nq < 16; nq++) {
      float4 Bq = B4[nq];
      h[nq * 4 + 0] = h[nq * 4 + 0] * dav + a * Bq.x;
      h[nq * 4 + 1] = h[nq * 4 + 1] * dav + a * Bq.y;
      h[nq * 4 + 2] = h[nq * 4 + 2] * dav + a * Bq.z;
      h[nq * 4 + 3] = h[nq * 4 + 3] * dav + a * Bq.w;
    }
    q *= dav;
  }
  float* Hp = H + ((size_t)bh * NSEG + seg) * 4096 + p * 64;
#pragma unroll
  for (int nq = 0; nq < 16; nq++)
    *(float4*)&Hp[nq * 4] = make_float4(h[nq*4], h[nq*4+1], h[nq*4+2], h[nq*4+3]);
  if (p == 0) QS[bh * NSEG + seg] = q;
}

// ---------------- scan combine ----------------
__global__ __launch_bounds__(64) void scomb_kernel(float* __restrict__ H,
    const float* __restrict__ QS) {
  int bh = blockIdx.x;
  int e = (blockIdx.y * 64 + threadIdx.x) * 4;
  float4 cur = make_float4(0.f, 0.f, 0.f, 0.f);
  for (int s = 0; s < NSEG; s++) {
    float* Hp = H + ((size_t)bh * NSEG + s) * 4096 + e;
    float q = QS[bh * NSEG + s];
    float4 tmp = *(float4*)Hp;
    *(float4*)Hp = cur;
    cur.x = q * cur.x + tmp.x;
    cur.y = q * cur.y + tmp.y;
    cur.z = q * cur.z + tmp.z;
    cur.w = q * cur.w + tmp.w;
  }
}

// ---------------- scan pass 2 ----------------
__global__ __launch_bounds__(64) void scan2_kernel(const float* __restrict__ XC,
    const float* __restrict__ dtp, const float* __restrict__ dAv,
    const float* __restrict__ H, const float* __restrict__ Dp,
    unsigned short* __restrict__ Ybf) {
  int seg = blockIdx.x, bh = blockIdx.y;
  int b = bh / NHM, head = bh - b * NHM;
  int p = threadIdx.x;
  float h[64];
  const float* Hp = H + ((size_t)bh * NSEG + seg) * 4096 + p * 64;
#pragma unroll
  for (int nq = 0; nq < 16; nq++) {
    float4 h4 = *(const float4*)&Hp[nq * 4];
    h[nq*4] = h4.x; h[nq*4+1] = h4.y; h[nq*4+2] = h4.z; h[nq*4+3] = h4.w;
  }
  float Dh = Dp[head];
  int l0 = seg * SEGLEN;
  const float* xcb = XC + ((size_t)b * L_SEQ + l0) * CONVD;
  const float* dtb = dtp + ((size_t)b * L_SEQ + l0) * NHM + head;
  const float* dab = dAv + ((size_t)b * L_SEQ + l0) * NHM + head;
  unsigned short* yb = Ybf + ((size_t)b * L_SEQ + l0) * DIN + head * HDM + p;
  int xcol = head * HDM + p;
  for (int i = 0; i < SEGLEN; i++) {
    const float* rowp = xcb + (size_t)i * CONVD;
    float xv = rowp[xcol];
    float dtv = dtb[(size_t)i * NHM];
    float dav = dab[(size_t)i * NHM];
    float a = dtv * xv;
    const float4* B4 = (const float4*)&rowp[768];
    const float4* C4 = (const float4*)&rowp[832];
    float y0 = 0.f, y1 = 0.f, y2 = 0.f, y3 = 0.f;
#pragma unroll
    for (int nq = 0; nq < 16; nq++) {
      float4 Bq = B4[nq];
      float4 Cq = C4[nq];
      h[nq * 4 + 0] = h[nq * 4 + 0] * dav + a * Bq.x;
      h[nq * 4 + 1] = h[nq * 4 + 1] * dav + a * Bq.y;
      h[nq * 4 + 2] = h[nq * 4 + 2] * dav + a * Bq.z;
      h[nq * 4 + 3] = h[nq * 4 + 3] * dav + a * Bq.w;
      y0 += h[nq * 4 + 0] * Cq.x;
      y1 += h[nq * 4 + 1] * Cq.y;
      y2 += h[nq * 4 + 2] * Cq.z;
      y3 += h[nq * 4 + 3] * Cq.w;
    }
    float yp = (y0 + y1) + (y2 + y3) + Dh * xv;
    yb[(size_t)i * DIN] = f2bf(yp);
  }
}

// ---------------- gated RMS norm (full) ----------------
__global__ __launch_bounds__(256) void gate_rms_kernel(unsigned short* __restrict__ Y,
    const float* __restrict__ Z, const float* __restrict__ mw) {
  int wave = threadIdx.x >> 6, lane = threadIdx.x & 63;
  int row = blockIdx.x * 4 + wave;
  if (row >= NROWS) return;
  unsigned short* y = Y + (size_t)row * DIN;
  const float* z = Z + (size_t)row * DIN;
  float g[12];
  float ss = 0.f;
#pragma unroll
  for (int q = 0; q < 3; q++) {
    int c = q * 256 + lane * 4;
    uint2 yu = *(const uint2*)&y[c];
    float4 zv = *(const float4*)&z[c];
    float y0 = bf2f((unsigned short)(yu.x & 0xffff));
    float y1 = bf2f((unsigned short)(yu.x >> 16));
    float y2 = bf2f((unsigned short)(yu.y & 0xffff));
    float y3 = bf2f((unsigned short)(yu.y >> 16));
    float g0 = y0 * siluf(zv.x), g1 = y1 * siluf(zv.y);
    float g2 = y2 * siluf(zv.z), g3 = y3 * siluf(zv.w);
    ss += g0 * g0 + g1 * g1 + g2 * g2 + g3 * g3;
    g[q * 4 + 0] = g0; g[q * 4 + 1] = g1; g[q * 4 + 2] = g2; g[q * 4 + 3] = g3;
  }
#pragma unroll
  for (int o = 32; o > 0; o >>= 1) ss += __shfl_xor(ss, o, 64);
  float rs = rsqrtf(ss * (1.f / 768.f) + 1e-5f);
#pragma unroll
  for (int q = 0; q < 3; q++) {
    int c = q * 256 + lane * 4;
    float4 m = *(const float4*)&mw[c];
    unsigned int lo = (unsigned int)f2bf(g[q*4+0] * rs * m.x) | ((unsigned int)f2bf(g[q*4+1] * rs * m.y) << 16);
    unsigned int hi = (unsigned int)f2bf(g[q*4+2] * rs * m.z) | ((unsigned int)f2bf(g[q*4+3] * rs * m.w) << 16);
    uint2 pk; pk.x = lo; pk.y = hi;
    *(uint2*)&y[c] = pk;
  }
}

// ---------------- attention gate ----------------
__global__ __launch_bounds__(256) void attgate_kernel(const unsigned short* __restrict__ XN,
    const float* __restrict__ gw, const float* __restrict__ gb, float* __restrict__ G) {
  int wave = threadIdx.x >> 6, lane = threadIdx.x & 63;
  int row = blockIdx.x * 4 + wave;
  if (row >= NROWS) return;
  const unsigned short* x = XN + (size_t)row * CDIM;
  float acc[12] = {};
#pragma unroll
  for (int q = 0; q < 6; q++) {
    int k = q * 64 + lane;
    float xv = bf2f(x[k]);
    const float* wr = gw + (size_t)k * 12;
    float4 w0 = *(const float4*)&wr[0];
    float4 w1 = *(const float4*)&wr[4];
    float4 w2 = *(const float4*)&wr[8];
    acc[0] += xv * w0.x; acc[1] += xv * w0.y; acc[2]  += xv * w0.z; acc[3]  += xv * w0.w;
    acc[4] += xv * w1.x; acc[5] += xv * w1.y; acc[6]  += xv * w1.z; acc[7]  += xv * w1.w;
    acc[8] += xv * w2.x; acc[9] += xv * w2.y; acc[10] += xv * w2.z; acc[11] += xv * w2.w;
  }
#pragma unroll
  for (int h = 0; h < 12; h++)
#pragma unroll
    for (int o = 32; o > 0; o >>= 1) acc[h] += __shfl_xor(acc[h], o, 64);
  if (lane == 0) {
#pragma unroll
    for (int h = 0; h < 12; h++) {
      float v = acc[h] + gb[h];
      G[(size_t)row * 12 + h] = 1.f / (1.f + expf(-v));
    }
  }
}

// ---------------- windowed attention; conflict-free LDS layout ----------------
// qs: [49][33] (pad 33 -> distinct banks per qi), ks transposed [32][52]
// (cols padded 49->52, zero-filled), ps: [49][52] (aligned float4 stores).
__global__ __launch_bounds__(256) void attn_kernel(const unsigned short* __restrict__ QKV,
    const float* __restrict__ G, unsigned short* __restrict__ XA) {
  __shared__ float qs[49 * 33];
  __shared__ float kst[32 * 52];
  __shared__ float vs[49 * 32];
  __shared__ float ps[49 * 52];
  int blk = blockIdx.x;
  int head = blk % NHA;
  int win = blk / NHA;          // [0, 512)
  int b = win >> 6;
  int wr = win & 63;
  int wy = wr >> 3, wx = wr & 7;
  int t = threadIdx.x;
  const float scale = 0.17677669529663688f;

  for (int e = t; e < 1568; e += 256) {
    int tok = e >> 5, d = e & 31;
    int iy = tok / 7, ix = tok - iy * 7;
    size_t rl = (size_t)b * L_SEQ + (wy * 7 + iy) * 56 + (wx * 7 + ix);
    const unsigned short* qp = QKV + rl * 1152 + head * 32 + d;
    qs[tok * 33 + d] = bf2f(qp[0]) * scale;
    kst[d * 52 + tok] = bf2f(qp[384]);
    vs[tok * 32 + d] = bf2f(qp[768]);
  }
  // zero-fill K pad columns 49..51
  if (t < 96) kst[(t & 31) * 52 + 49 + (t >> 5)] = 0.f;
  __syncthreads();

  // S = Q K^T : each thread computes 4 adjacent kj via float4 (conflict-free)
  for (int e = t; e < 637; e += 256) {   // 49 qi * 13 groups
    int qi = e / 13, g = e - qi * 13;
    const float* qrow = &qs[qi * 33];
    float4 acc = make_float4(0.f, 0.f, 0.f, 0.f);
#pragma unroll
    for (int dd = 0; dd < 32; dd++) {
      float qv = qrow[dd];
      float4 kv = *(const float4*)&kst[dd * 52 + g * 4];
      acc.x += qv * kv.x; acc.y += qv * kv.y;
      acc.z += qv * kv.z; acc.w += qv * kv.w;
    }
    *(float4*)&ps[qi * 52 + g * 4] = acc;
  }
  __syncthreads();
  if (t < 49) {
    float* pr = &ps[t * 52];
    float m = pr[0];
    for (int j = 1; j < 49; j++) m = fmaxf(m, pr[j]);
    float s = 0.f;
    for (int j = 0; j < 49; j++) { float e2 = expf(pr[j] - m); pr[j] = e2; s += e2; }
    float inv = 1.f / s;
    for (int j = 0; j < 49; j++) pr[j] *= inv;
  }
  __syncthreads();
  for (int e = t; e < 1568; e += 256) {
    int qi = e >> 5, d = e & 31;
    const float* pr = &ps[qi * 52];
    float acc = 0.f;
    for (int j = 0; j < 49; j++) acc += pr[j] * vs[j * 32 + d];
    int iy = qi / 7, ix = qi - iy * 7;
    size_t rg = (size_t)b * L_SEQ + (wy * 7 + iy) * 56 + (wx * 7 + ix);
    float g = G[rg * 12 + head];
    XA[rg * CDIM + head * 32 + d] = f2bf(acc * g);
  }
}

// ---------------- host launch ----------------
extern "C" void kernel_launch(void* const* d_in, const int* in_sizes, int n_in,
                              void* d_out, int out_size, void* d_ws, size_t ws_size,
                              hipStream_t stream) {
  const float* x        = (const float*)d_in[0];
  const float* norm1_w  = (const float*)d_in[1];
  const float* norm1_b  = (const float*)d_in[2];
  const float* W_in     = (const float*)d_in[3];
  const float* conv_w   = (const float*)d_in[4];
  const float* conv_b   = (const float*)d_in[5];
  const float* dt_bias  = (const float*)d_in[6];
  const float* A_log    = (const float*)d_in[7];
  const float* Dp       = (const float*)d_in[8];
  const float* mnorm_w  = (const float*)d_in[9];
  const float* W_out    = (const float*)d_in[10];
  const float* qkv_w    = (const float*)d_in[11];
  const float* qkv_b    = (const float*)d_in[12];
  const float* gate_w   = (const float*)d_in[13];
  const float* gate_b   = (const float*)d_in[14];
  const float* proj_w   = (const float*)d_in[15];
  const float* proj_b   = (const float*)d_in[16];
  const float* fusion_w = (const float*)d_in[17];
  const float* fusion_b = (const float*)d_in[18];
  const float* norm2_w  = (const float*)d_in[19];
  const float* norm2_b  = (const float*)d_in[20];
  const float* fc1_w    = (const float*)d_in[21];
  const float* fc1_b    = (const float*)d_in[22];
  const float* fc2_w    = (const float*)d_in[23];
  const float* fc2_b    = (const float*)d_in[24];
  float* OUT = (float*)d_out;

  float* ws = (float*)d_ws;
  unsigned short* XNBF = (unsigned short*)ws;              // 25088x384 bf16 (4,816,896 fl)
  float* XC_  = ws + 4816896;                              // XC fp32 full (22,478,848 fl); later CATBF+XABF
  float* SCR  = XC_ + 22478848;                            // xBC fp32 -> H -> z fp32 -> QKVbf -> M1bf
  unsigned short* YBF = (unsigned short*)(SCR + 22478848); // 25088x768 bf16 (9,633,792 fl)
  unsigned short* WT  = (unsigned short*)(SCR + 22478848 + 9633792); // 3,047,424 bf16
  float* DT_ = (float*)(WT + 3047424);                     // 301,056
  float* DA_ = DT_ + 301056;                               // 301,056
  float* G_  = DA_ + 301056;                               // 301,056
  float* QS_ = G_  + 301056;                               // 5,376

  float* H_ = SCR;
  float* Zf = SCR;
  unsigned short* QKVBF = (unsigned short*)SCR;
  unsigned short* M1BF  = (unsigned short*)SCR;
  unsigned short* CATBF = (unsigned short*)XC_;
  unsigned short* XABF  = (unsigned short*)(XC_ + 9633792);

  unsigned short* wt_xbc  = WT;            // 896x384
  unsigned short* wt_dt   = WT + 344064;   // 128x384
  unsigned short* wt_z    = WT + 393216;   // 768x384
  unsigned short* wt_out  = WT + 688128;   // 384x768
  unsigned short* wt_qkv  = WT + 983040;   // 1152x384
  unsigned short* wt_proj = WT + 1425408;  // 384x384
  unsigned short* wt_fus  = WT + 1572864;  // 384x768
  unsigned short* wt_fc1  = WT + 1867776;  // 1536x384
  unsigned short* wt_fc2  = WT + 2457600;  // 384x1536

  wconv_kernel<<<dim3(12,  28), 256, 0, stream>>>(W_in + 768,  wt_xbc,  384,  896, DPROJ);
  wconv_kernel<<<dim3(12,   4), 256, 0, stream>>>(W_in + 1664, wt_dt,   384,   12, DPROJ);
  wconv_kernel<<<dim3(12,  24), 256, 0, stream>>>(W_in,        wt_z,    384,  768, DPROJ);
  wconv_kernel<<<dim3(24,  12), 256, 0, stream>>>(W_out,       wt_out,  768,  384, 384);
  wconv_kernel<<<dim3(12,  36), 256, 0, stream>>>(qkv_w,       wt_qkv,  384, 1152, 1152);
  wconv_kernel<<<dim3(12,  12), 256, 0, stream>>>(proj_w,      wt_proj, 384,  384, 384);
  wconv_kernel<<<dim3(24,  12), 256, 0, stream>>>(fusion_w,    wt_fus,  768,  384, 384);
  wconv_kernel<<<dim3(12,  48), 256, 0, stream>>>(fc1_w,       wt_fc1,  384, 1536, 1536);
  wconv_kernel<<<dim3(48,  12), 256, 0, stream>>>(fc2_w,       wt_fc2, 1536,  384, 384);

  ln_kernel<<<6272, 256, 0, stream>>>(x, norm1_w, norm1_b, XNBF);

  gemm_bf<0, false, false, false><<<dim3(7, 196), 256, 0, stream>>>(
      XNBF, wt_xbc, SCR, nullptr, nullptr, 0, NROWS, CONVD, CDIM, CDIM, CONVD, 0);
  conv_kernel<<<(NROWS * CONVD + 255) / 256, 256, 0, stream>>>(SCR, conv_w, conv_b, XC_);
  gemm_bf<0, false, false, false><<<dim3(1, 196), 256, 0, stream>>>(
      XNBF, wt_dt, DT_, nullptr, nullptr, 0, NROWS, NHM, CDIM, CDIM, NHM, 0);

  dtprep_kernel<<<(NROWS * NHM + 255) / 256, 256, 0, stream>>>(DT_, dt_bias, A_log, DA_);

  scan1_kernel<<<dim3(NSEG, 96), 64, 0, stream>>>(XC_, DT_, DA_, H_, QS_);
  scomb_kernel<<<dim3(96, 16), 64, 0, stream>>>(H_, QS_);
  scan2_kernel<<<dim3(NSEG, 96), 64, 0, stream>>>(XC_, DT_, DA_, H_, Dp, YBF);

  gemm_bf<0, false, false, false><<<dim3(6, 196), 256, 0, stream>>>(
      XNBF, wt_z, Zf, nullptr, nullptr, 0, NROWS, DIN, CDIM, CDIM, DIN, 0);
  gate_rms_kernel<<<6272, 256, 0, stream>>>(YBF, Zf, mnorm_w);

  gemm_bf<0, false, false, true><<<dim3(3, 196), 256, 0, stream>>>(
      YBF, wt_out, CATBF, nullptr, nullptr, 0, NROWS, CDIM, DIN, DIN, 2 * CDIM, 0);

  attgate_kernel<<<6272, 256, 0, stream>>>(XNBF, gate_w, gate_b, G_);

  gemm_bf<0, true, false, true><<<dim3(9, 196), 256, 0, stream>>>(
      XNBF, wt_qkv, QKVBF, qkv_b, nullptr, 0, NROWS, 3 * CDIM, CDIM, CDIM, 3 * CDIM, 0);
  attn_kernel<<<512 * NHA, 256, 0, stream>>>(QKVBF, G_, XABF);

  gemm_bf<0, true, false, true><<<dim3(3, 196), 256, 0, stream>>>(
      XABF, wt_proj, CATBF, proj_b, nullptr, 0, NROWS, CDIM, CDIM, CDIM, 2 * CDIM, CDIM);

  gemm_bf<0, true, true, false><<<dim3(3, 196), 256, 0, stream>>>(
      CATBF, wt_fus, OUT, fusion_b, x, CDIM, NROWS, CDIM, 2 * CDIM, 2 * CDIM, CDIM, 0);

  ln_kernel<<<6272, 256, 0, stream>>>(OUT, norm2_w, norm2_b, XNBF);

  gemm_bf<1, true, false, true><<<dim3(12, 196), 256, 0, stream>>>(
      XNBF, wt_fc1, M1BF, fc1_b, nullptr, 0, NROWS, 4 * CDIM, CDIM, CDIM, 4 * CDIM, 0);
  gemm_bf<0, true, true, false><<<dim3(3, 196), 256, 0, stream>>>(
      M1BF, wt_fc2, OUT, fc2_b, OUT, CDIM, NROWS, CDIM, 4 * CDIM, 4 * CDIM, CDIM, 0);
}